// Round 1
// baseline (1392.792 us; speedup 1.0000x reference)
//
#include <hip/hip_runtime.h>
#include <hip/hip_bf16.h>
#include <cstdint>

using bf16 = __hip_bfloat16;
typedef __bf16 bf16x8 __attribute__((ext_vector_type(8)));
typedef float f32x4 __attribute__((ext_vector_type(4)));

constexpr int Hd = 512;
constexpr int Ld = 6;
constexpr int Fd = 2048;
constexpr int Vd = 50304;
constexpr int Md = 4096;  // B*S = 4*1024

// ---------- helpers ----------
__device__ __forceinline__ unsigned short f2b(float x) {
  return __builtin_bit_cast(unsigned short, __float2bfloat16(x));
}

__device__ __forceinline__ float gelu_tanh(float x) {
  const float c = 0.7978845608028654f;  // sqrt(2/pi)
  float x3 = x * x * x;
  return 0.5f * x * (1.0f + tanhf(c * (x + 0.044715f * x3)));
}

__device__ __forceinline__ void load16_lds(const bf16* g, bf16* l) {
  __builtin_amdgcn_global_load_lds(
      (const __attribute__((address_space(1))) void*)g,
      (__attribute__((address_space(3))) void*)l, 16, 0, 0);
}

// ---------- cast fp32 -> bf16, 8 elems/thread ----------
__global__ __launch_bounds__(256) void cast8(const float* __restrict__ in,
                                             bf16* __restrict__ out, int n8) {
  int i = blockIdx.x * 256 + threadIdx.x;
  if (i >= n8) return;
  const float4* p = (const float4*)in;
  float4 a = p[2 * i], b = p[2 * i + 1];
  uint4 o = {(unsigned)f2b(a.x) | ((unsigned)f2b(a.y) << 16),
             (unsigned)f2b(a.z) | ((unsigned)f2b(a.w) << 16),
             (unsigned)f2b(b.x) | ((unsigned)f2b(b.y) << 16),
             (unsigned)f2b(b.z) | ((unsigned)f2b(b.w) << 16)};
  ((uint4*)out)[i] = o;
}

// ---------- transpose+cast: in (R,C) f32 -> out (C,R) bf16, batched over z ----------
__global__ void transpose_cast(const float* __restrict__ in, bf16* __restrict__ out,
                               int R, int C) {
  __shared__ float tile[32][33];
  int l = blockIdx.z;
  in += (size_t)l * R * C;
  out += (size_t)l * R * C;
  int c0 = blockIdx.x * 32, r0 = blockIdx.y * 32;
#pragma unroll
  for (int i = 0; i < 4; i++) {
    int r = r0 + threadIdx.y + i * 8;
    tile[threadIdx.y + i * 8][threadIdx.x] = in[(size_t)r * C + c0 + threadIdx.x];
  }
  __syncthreads();
#pragma unroll
  for (int i = 0; i < 4; i++) {
    int c = c0 + threadIdx.y + i * 8;
    out[(size_t)c * R + r0 + threadIdx.x] = (bf16)tile[threadIdx.x][threadIdx.y + i * 8];
  }
}

// ---------- embedding gather ----------
__global__ void gather_embed(const int* __restrict__ ids, const float* __restrict__ emb,
                             float* __restrict__ h) {
  int row = blockIdx.x;
  int id = ids[row];
  const float4* src = (const float4*)(emb + (size_t)id * Hd);
  float4* dst = (float4*)(h + (size_t)row * Hd);
  dst[threadIdx.x] = src[threadIdx.x];
}

// ---------- layernorm (fp32 in) -> bf16 out, one wave per row ----------
__global__ __launch_bounds__(256) void ln_rows(const float* __restrict__ h,
                                               const float* __restrict__ w,
                                               const float* __restrict__ b,
                                               bf16* __restrict__ y) {
  int row = blockIdx.x * 4 + (threadIdx.x >> 6);
  int lane = threadIdx.x & 63;
  const float4* x = (const float4*)(h + (size_t)row * Hd);
  float xv[8];
  *(float4*)&xv[0] = x[lane * 2];
  *(float4*)&xv[4] = x[lane * 2 + 1];
  float s = 0.f;
#pragma unroll
  for (int j = 0; j < 8; j++) s += xv[j];
#pragma unroll
  for (int off = 1; off < 64; off <<= 1) s += __shfl_xor(s, off);
  float mu = s * (1.0f / 512.0f);
  float s2 = 0.f;
#pragma unroll
  for (int j = 0; j < 8; j++) {
    xv[j] -= mu;
    s2 += xv[j] * xv[j];
  }
#pragma unroll
  for (int off = 1; off < 64; off <<= 1) s2 += __shfl_xor(s2, off);
  float scale = rsqrtf(s2 * (1.0f / 512.0f) + 1e-5f);
  float o[8];
#pragma unroll
  for (int j = 0; j < 8; j++) {
    float wj = w[lane * 8 + j], bj = b[lane * 8 + j];
    o[j] = xv[j] * scale * wj + bj;
  }
  uint4 pk = {(unsigned)f2b(o[0]) | ((unsigned)f2b(o[1]) << 16),
              (unsigned)f2b(o[2]) | ((unsigned)f2b(o[3]) << 16),
              (unsigned)f2b(o[4]) | ((unsigned)f2b(o[5]) << 16),
              (unsigned)f2b(o[6]) | ((unsigned)f2b(o[7]) << 16)};
  *(uint4*)(y + (size_t)row * Hd + lane * 8) = pk;
}

// ---------- GEMM: C(M,N) = A(M,K) @ Bt(N,K)^T, bf16 inputs, fp32 accum ----------
// EPI 0: out_bf16 = gelu(acc + bias)   (for W1/gelu)
// EPI 1: out_f32  = acc + bias + res   (for W2 + residual)
// EPI 2: out_f32  = acc + bias         (for hp)
// EPI 3: out_f32  = acc                (for logits)
template <int EPI>
__global__ __launch_bounds__(256) void gemm_bt(
    const bf16* __restrict__ A, const bf16* __restrict__ Bt,
    const float* __restrict__ bias, const float* __restrict__ res,
    float* __restrict__ outF, bf16* __restrict__ outB, int M, int N, int K) {
  __shared__ bf16 lds[2 * 128 * 32];
  bf16* ldsA = lds;
  bf16* ldsB = lds + 128 * 32;
  const int tid = threadIdx.x;
  const int wave = tid >> 6;
  const int lane = tid & 63;
  const int wm = (wave >> 1) * 64;
  const int wn = (wave & 1) * 64;
  const int rowA0 = blockIdx.y * 128;
  const int rowB0 = blockIdx.x * 128;

  f32x4 acc[4][4];
#pragma unroll
  for (int i = 0; i < 4; i++)
#pragma unroll
    for (int j = 0; j < 4; j++) acc[i][j] = (f32x4){0.f, 0.f, 0.f, 0.f};

  const int fr = lane & 15;       // fragment row (within 16)
  const int ko = (lane >> 4) * 8; // k offset within BK=32

  for (int kt = 0; kt < K; kt += 32) {
#pragma unroll
    for (int r = 0; r < 2; r++) {
      const int c = (r * 4 + wave) * 64 + lane;
      const int row = c >> 2, cw = c & 3;
      load16_lds(A + (size_t)(rowA0 + row) * K + kt + cw * 8,
                 ldsA + (size_t)(r * 4 + wave) * 512);
      load16_lds(Bt + (size_t)(rowB0 + row) * K + kt + cw * 8,
                 ldsB + (size_t)(r * 4 + wave) * 512);
    }
    __syncthreads();
    bf16x8 af[4], bfr[4];
#pragma unroll
    for (int f = 0; f < 4; f++) {
      af[f] = *(const bf16x8*)(ldsA + (wm + f * 16 + fr) * 32 + ko);
      bfr[f] = *(const bf16x8*)(ldsB + (wn + f * 16 + fr) * 32 + ko);
    }
#pragma unroll
    for (int i = 0; i < 4; i++)
#pragma unroll
      for (int j = 0; j < 4; j++)
        acc[i][j] = __builtin_amdgcn_mfma_f32_16x16x32_bf16(af[i], bfr[j], acc[i][j], 0, 0, 0);
    __syncthreads();
  }

  const int orow = (lane >> 4) * 4;
  const int ocol = lane & 15;
#pragma unroll
  for (int i = 0; i < 4; i++) {
#pragma unroll
    for (int j = 0; j < 4; j++) {
      int row0 = rowA0 + wm + i * 16 + orow;
      int col = rowB0 + wn + j * 16 + ocol;
#pragma unroll
      for (int q = 0; q < 4; q++) {
        float v = acc[i][j][q];
        size_t idx = (size_t)(row0 + q) * N + col;
        if constexpr (EPI == 0) {
          outB[idx] = (bf16)gelu_tanh(v + bias[col]);
        } else if constexpr (EPI == 1) {
          outF[idx] = v + bias[col] + res[idx];
        } else if constexpr (EPI == 2) {
          outF[idx] = v + bias[col];
        } else {
          outF[idx] = v;
        }
      }
    }
  }
}

// ---------- final hidden: h[:, -1, :] -> out ----------
__global__ void tail_copy(const float* __restrict__ h, float* __restrict__ out) {
  int t = blockIdx.x * 256 + threadIdx.x;  // 0..2047
  int b = t >> 9, k = t & 511;
  out[t] = h[((size_t)(b * 1024 + 1023)) * Hd + k];
}

// ---------- launch ----------
extern "C" void kernel_launch(void* const* d_in, const int* in_sizes, int n_in,
                              void* d_out, int out_size, void* d_ws, size_t ws_size,
                              hipStream_t stream) {
  const int* ids = (const int*)d_in[0];
  const float* emb = (const float*)d_in[1];
  const float* hp_w = (const float*)d_in[2];
  const float* hp_b = (const float*)d_in[3];
  const float* ln_w = (const float*)d_in[4];
  const float* ln_b = (const float*)d_in[5];
  const float* W1 = (const float*)d_in[6];
  const float* b1 = (const float*)d_in[7];
  const float* W2 = (const float*)d_in[8];
  const float* b2 = (const float*)d_in[9];
  const float* lnf_w = (const float*)d_in[10];
  const float* lnf_b = (const float*)d_in[11];
  const float* eow = (const float*)d_in[12];
  float* out = (float*)d_out;

  char* ws = (char*)d_ws;
  float* h = (float*)(ws);                          // 8 MB
  bf16* ybf = (bf16*)(ws + (8u << 20));             // 4 MB (LN out / h cast / normed)
  bf16* abf = (bf16*)(ws + (12u << 20));            // 16 MB (gelu activations)
  bf16* W1t = (bf16*)(ws + (28u << 20));            // 12 MB
  bf16* W2t = (bf16*)(ws + (40u << 20));            // 12 MB
  bf16* hpwB = (bf16*)(ws + (52u << 20));           // 0.5 MB
  bf16* eowB = (bf16*)(ws + (53u << 20));           // 51.5 MB

  // weight prep (bf16 cast; W1/W2 transposed to (N,K))
  cast8<<<dim3(Vd * Hd / 8 / 256), dim3(256), 0, stream>>>(eow, eowB, Vd * Hd / 8);
  cast8<<<dim3(Hd * Hd / 8 / 256), dim3(256), 0, stream>>>(hp_w, hpwB, Hd * Hd / 8);
  transpose_cast<<<dim3(Fd / 32, Hd / 32, Ld), dim3(32, 8), 0, stream>>>(W1, W1t, Hd, Fd);
  transpose_cast<<<dim3(Hd / 32, Fd / 32, Ld), dim3(32, 8), 0, stream>>>(W2, W2t, Fd, Hd);

  gather_embed<<<dim3(Md), dim3(128), 0, stream>>>(ids, emb, h);

  auto stack = [&]() {
    for (int l = 0; l < Ld; l++) {
      ln_rows<<<dim3(Md / 4), dim3(256), 0, stream>>>(h, ln_w + l * Hd, ln_b + l * Hd, ybf);
      gemm_bt<0><<<dim3(Fd / 128, Md / 128), dim3(256), 0, stream>>>(
          ybf, W1t + (size_t)l * Fd * Hd, b1 + (size_t)l * Fd,
          (const float*)nullptr, (float*)nullptr, abf, Md, Fd, Hd);
      gemm_bt<1><<<dim3(Hd / 128, Md / 128), dim3(256), 0, stream>>>(
          abf, W2t + (size_t)l * Hd * Fd, b2 + (size_t)l * Hd,
          h, h, (bf16*)nullptr, Md, Hd, Fd);
    }
  };

  stack();
  // h = h @ hp_w^T + hp_b
  cast8<<<dim3(Md * Hd / 8 / 256), dim3(256), 0, stream>>>(h, ybf, Md * Hd / 8);
  gemm_bt<2><<<dim3(Hd / 128, Md / 128), dim3(256), 0, stream>>>(
      ybf, hpwB, hp_b, (const float*)nullptr, h, (bf16*)nullptr, Md, Hd, Hd);
  stack();

  // final LN + logits
  ln_rows<<<dim3(Md / 4), dim3(256), 0, stream>>>(h, lnf_w, lnf_b, ybf);
  gemm_bt<3><<<dim3(Vd / 128, Md / 128), dim3(256), 0, stream>>>(
      ybf, eowB, (const float*)nullptr, (const float*)nullptr, out, (bf16*)nullptr,
      Md, Vd, Hd);

  // final hidden
  tail_copy<<<dim3(8), dim3(256), 0, stream>>>(h, out + (size_t)Md * Vd);
}

// Round 2
// 1255.629 us; speedup vs baseline: 1.1092x; 1.1092x over previous
//
#include <hip/hip_runtime.h>
#include <hip/hip_bf16.h>
#include <cstdint>

using bf16 = __hip_bfloat16;
typedef __bf16 bf16x8 __attribute__((ext_vector_type(8)));
typedef float f32x4 __attribute__((ext_vector_type(4)));

constexpr int Hd = 512;
constexpr int Ld = 6;
constexpr int Fd = 2048;
constexpr int Vd = 50304;
constexpr int Md = 4096;  // B*S = 4*1024

// ---------- helpers ----------
__device__ __forceinline__ unsigned short f2b(float x) {
  return __builtin_bit_cast(unsigned short, __float2bfloat16(x));
}

__device__ __forceinline__ float gelu_tanh(float x) {
  const float c = 0.7978845608028654f;  // sqrt(2/pi)
  float x3 = x * x * x;
  return 0.5f * x * (1.0f + tanhf(c * (x + 0.044715f * x3)));
}

__device__ __forceinline__ void load16_lds(const bf16* g, bf16* l) {
  __builtin_amdgcn_global_load_lds(
      (const __attribute__((address_space(1))) void*)g,
      (__attribute__((address_space(3))) void*)l, 16, 0, 0);
}

// ---------- cast fp32 -> bf16, 8 elems/thread ----------
__global__ __launch_bounds__(256) void cast8(const float* __restrict__ in,
                                             bf16* __restrict__ out, int n8) {
  int i = blockIdx.x * 256 + threadIdx.x;
  if (i >= n8) return;
  const float4* p = (const float4*)in;
  float4 a = p[2 * i], b = p[2 * i + 1];
  uint4 o = {(unsigned)f2b(a.x) | ((unsigned)f2b(a.y) << 16),
             (unsigned)f2b(a.z) | ((unsigned)f2b(a.w) << 16),
             (unsigned)f2b(b.x) | ((unsigned)f2b(b.y) << 16),
             (unsigned)f2b(b.z) | ((unsigned)f2b(b.w) << 16)};
  ((uint4*)out)[i] = o;
}

// ---------- transpose+cast: in (R,C) f32 -> out (C,R) bf16, batched over z ----------
__global__ void transpose_cast(const float* __restrict__ in, bf16* __restrict__ out,
                               int R, int C) {
  __shared__ float tile[32][33];
  int l = blockIdx.z;
  in += (size_t)l * R * C;
  out += (size_t)l * R * C;
  int c0 = blockIdx.x * 32, r0 = blockIdx.y * 32;
#pragma unroll
  for (int i = 0; i < 4; i++) {
    int r = r0 + threadIdx.y + i * 8;
    tile[threadIdx.y + i * 8][threadIdx.x] = in[(size_t)r * C + c0 + threadIdx.x];
  }
  __syncthreads();
#pragma unroll
  for (int i = 0; i < 4; i++) {
    int c = c0 + threadIdx.y + i * 8;
    out[(size_t)c * R + r0 + threadIdx.x] = (bf16)tile[threadIdx.x][threadIdx.y + i * 8];
  }
}

// ---------- embedding gather ----------
__global__ void gather_embed(const int* __restrict__ ids, const float* __restrict__ emb,
                             float* __restrict__ h) {
  int row = blockIdx.x;
  int id = ids[row];
  const float4* src = (const float4*)(emb + (size_t)id * Hd);
  float4* dst = (float4*)(h + (size_t)row * Hd);
  dst[threadIdx.x] = src[threadIdx.x];
}

// ---------- layernorm (fp32 in) -> bf16 out, one wave per row ----------
__global__ __launch_bounds__(256) void ln_rows(const float* __restrict__ h,
                                               const float* __restrict__ w,
                                               const float* __restrict__ b,
                                               bf16* __restrict__ y) {
  int row = blockIdx.x * 4 + (threadIdx.x >> 6);
  int lane = threadIdx.x & 63;
  const float4* x = (const float4*)(h + (size_t)row * Hd);
  float xv[8];
  *(float4*)&xv[0] = x[lane * 2];
  *(float4*)&xv[4] = x[lane * 2 + 1];
  float s = 0.f;
#pragma unroll
  for (int j = 0; j < 8; j++) s += xv[j];
#pragma unroll
  for (int off = 1; off < 64; off <<= 1) s += __shfl_xor(s, off);
  float mu = s * (1.0f / 512.0f);
  float s2 = 0.f;
#pragma unroll
  for (int j = 0; j < 8; j++) {
    xv[j] -= mu;
    s2 += xv[j] * xv[j];
  }
#pragma unroll
  for (int off = 1; off < 64; off <<= 1) s2 += __shfl_xor(s2, off);
  float scale = rsqrtf(s2 * (1.0f / 512.0f) + 1e-5f);
  float o[8];
#pragma unroll
  for (int j = 0; j < 8; j++) {
    float wj = w[lane * 8 + j], bj = b[lane * 8 + j];
    o[j] = xv[j] * scale * wj + bj;
  }
  uint4 pk = {(unsigned)f2b(o[0]) | ((unsigned)f2b(o[1]) << 16),
              (unsigned)f2b(o[2]) | ((unsigned)f2b(o[3]) << 16),
              (unsigned)f2b(o[4]) | ((unsigned)f2b(o[5]) << 16),
              (unsigned)f2b(o[6]) | ((unsigned)f2b(o[7]) << 16)};
  *(uint4*)(y + (size_t)row * Hd + lane * 8) = pk;
}

// ---------- GEMM: C(M,BNgrid) = A(M,K) @ Bt(N,K)^T, bf16 in, fp32 accum ----------
// Tile: 128 (M) x BN (N), BK=32. BN in {64,128}.
// EPI 0: out_bf16 = gelu(acc + bias)   (W1/gelu)
// EPI 1: out_f32  = acc + bias + res   (W2 + residual)
// EPI 2: out_f32  = acc + bias         (hp)
// EPI 3: out_f32  = acc                (logits)
template <int EPI, int BN>
__global__ __launch_bounds__(256) void gemm_bt(
    const bf16* __restrict__ A, const bf16* __restrict__ Bt,
    const float* __restrict__ bias, const float* __restrict__ res,
    float* __restrict__ outF, bf16* __restrict__ outB, int M, int N, int K) {
  __shared__ bf16 lds[128 * 32 + BN * 32];
  bf16* ldsA = lds;
  bf16* ldsB = lds + 128 * 32;
  const int tid = threadIdx.x;
  const int wave = tid >> 6;
  const int lane = tid & 63;
  constexpr int NF = BN / 32;          // n-fragments per wave
  const int wm = (wave >> 1) * 64;     // wave m-origin
  const int wn = (wave & 1) * (BN / 2);// wave n-origin
  const int rowA0 = blockIdx.y * 128;
  const int rowB0 = blockIdx.x * BN;

  f32x4 acc[4][NF];
#pragma unroll
  for (int i = 0; i < 4; i++)
#pragma unroll
    for (int j = 0; j < NF; j++) acc[i][j] = (f32x4){0.f, 0.f, 0.f, 0.f};

  const int fr = lane & 15;        // fragment row (within 16)
  const int ko = (lane >> 4) * 8;  // k offset within BK=32

  for (int kt = 0; kt < K; kt += 32) {
    // A: 128x32 bf16 = 8KB -> 2 rounds of 256x16B
#pragma unroll
    for (int r = 0; r < 2; r++) {
      const int base = r * 4 + wave;
      const int c = base * 64 + lane;
      const int row = c >> 2, cw = c & 3;
      load16_lds(A + (size_t)(rowA0 + row) * K + kt + cw * 8,
                 ldsA + (size_t)base * 512);
    }
    // B: BNx32 bf16 -> BN/64 rounds
#pragma unroll
    for (int r = 0; r < BN / 64; r++) {
      const int base = r * 4 + wave;
      const int c = base * 64 + lane;
      const int row = c >> 2, cw = c & 3;
      load16_lds(Bt + (size_t)(rowB0 + row) * K + kt + cw * 8,
                 ldsB + (size_t)base * 512);
    }
    __syncthreads();
    bf16x8 af[4], bfr[NF];
#pragma unroll
    for (int f = 0; f < 4; f++)
      af[f] = *(const bf16x8*)(ldsA + (wm + f * 16 + fr) * 32 + ko);
#pragma unroll
    for (int f = 0; f < NF; f++)
      bfr[f] = *(const bf16x8*)(ldsB + (wn + f * 16 + fr) * 32 + ko);
#pragma unroll
    for (int i = 0; i < 4; i++)
#pragma unroll
      for (int j = 0; j < NF; j++)
        acc[i][j] = __builtin_amdgcn_mfma_f32_16x16x32_bf16(af[i], bfr[j], acc[i][j], 0, 0, 0);
    __syncthreads();
  }

  const int orow = (lane >> 4) * 4;
  const int ocol = lane & 15;
#pragma unroll
  for (int i = 0; i < 4; i++) {
#pragma unroll
    for (int j = 0; j < NF; j++) {
      int row0 = rowA0 + wm + i * 16 + orow;
      int col = rowB0 + wn + j * 16 + ocol;
#pragma unroll
      for (int q = 0; q < 4; q++) {
        float v = acc[i][j][q];
        size_t idx = (size_t)(row0 + q) * N + col;
        if constexpr (EPI == 0) {
          outB[idx] = (bf16)gelu_tanh(v + bias[col]);
        } else if constexpr (EPI == 1) {
          outF[idx] = v + bias[col] + res[idx];
        } else if constexpr (EPI == 2) {
          outF[idx] = v + bias[col];
        } else {
          outF[idx] = v;
        }
      }
    }
  }
}

// ---------- final hidden: h[:, -1, :] -> out ----------
__global__ void tail_copy(const float* __restrict__ h, float* __restrict__ out) {
  int t = blockIdx.x * 256 + threadIdx.x;  // 0..2047
  int b = t >> 9, k = t & 511;
  out[t] = h[((size_t)(b * 1024 + 1023)) * Hd + k];
}

// ---------- launch ----------
extern "C" void kernel_launch(void* const* d_in, const int* in_sizes, int n_in,
                              void* d_out, int out_size, void* d_ws, size_t ws_size,
                              hipStream_t stream) {
  const int* ids = (const int*)d_in[0];
  const float* emb = (const float*)d_in[1];
  const float* hp_w = (const float*)d_in[2];
  const float* hp_b = (const float*)d_in[3];
  const float* ln_w = (const float*)d_in[4];
  const float* ln_b = (const float*)d_in[5];
  const float* W1 = (const float*)d_in[6];
  const float* b1 = (const float*)d_in[7];
  const float* W2 = (const float*)d_in[8];
  const float* b2 = (const float*)d_in[9];
  const float* lnf_w = (const float*)d_in[10];
  const float* lnf_b = (const float*)d_in[11];
  const float* eow = (const float*)d_in[12];
  float* out = (float*)d_out;

  char* ws = (char*)d_ws;
  float* h = (float*)(ws);                          // 8 MB
  bf16* ybf = (bf16*)(ws + (8u << 20));             // 4 MB (LN out / h cast)
  bf16* abf = (bf16*)(ws + (12u << 20));            // 16 MB (gelu activations)
  bf16* W1t = (bf16*)(ws + (28u << 20));            // 12 MB
  bf16* W2t = (bf16*)(ws + (40u << 20));            // 12 MB
  bf16* hpwB = (bf16*)(ws + (52u << 20));           // 0.5 MB
  bf16* eowB = (bf16*)(ws + (53u << 20));           // 51.5 MB

  // weight prep (bf16 cast; W1/W2 transposed to (N,K))
  cast8<<<dim3(Vd * Hd / 8 / 256), dim3(256), 0, stream>>>(eow, eowB, Vd * Hd / 8);
  cast8<<<dim3(Hd * Hd / 8 / 256), dim3(256), 0, stream>>>(hp_w, hpwB, Hd * Hd / 8);
  transpose_cast<<<dim3(Fd / 32, Hd / 32, Ld), dim3(32, 8), 0, stream>>>(W1, W1t, Hd, Fd);
  transpose_cast<<<dim3(Hd / 32, Fd / 32, Ld), dim3(32, 8), 0, stream>>>(W2, W2t, Fd, Hd);

  gather_embed<<<dim3(Md), dim3(128), 0, stream>>>(ids, emb, h);

  auto stack = [&]() {
    for (int l = 0; l < Ld; l++) {
      ln_rows<<<dim3(Md / 4), dim3(256), 0, stream>>>(h, ln_w + l * Hd, ln_b + l * Hd, ybf);
      gemm_bt<0, 128><<<dim3(Fd / 128, Md / 128), dim3(256), 0, stream>>>(
          ybf, W1t + (size_t)l * Fd * Hd, b1 + (size_t)l * Fd,
          (const float*)nullptr, (float*)nullptr, abf, Md, Fd, Hd);
      // N=512: 64-wide N tiles -> 256 workgroups (full CU coverage)
      gemm_bt<1, 64><<<dim3(Hd / 64, Md / 128), dim3(256), 0, stream>>>(
          abf, W2t + (size_t)l * Hd * Fd, b2 + (size_t)l * Hd,
          h, h, (bf16*)nullptr, Md, Hd, Fd);
    }
  };

  stack();
  // h = h @ hp_w^T + hp_b   (N=512 -> BN=64)
  cast8<<<dim3(Md * Hd / 8 / 256), dim3(256), 0, stream>>>(h, ybf, Md * Hd / 8);
  gemm_bt<2, 64><<<dim3(Hd / 64, Md / 128), dim3(256), 0, stream>>>(
      ybf, hpwB, hp_b, (const float*)nullptr, h, (bf16*)nullptr, Md, Hd, Hd);
  stack();

  // final LN + logits
  ln_rows<<<dim3(Md / 4), dim3(256), 0, stream>>>(h, lnf_w, lnf_b, ybf);
  gemm_bt<3, 128><<<dim3(Vd / 128, Md / 128), dim3(256), 0, stream>>>(
      ybf, eowB, (const float*)nullptr, (const float*)nullptr, out, (bf16*)nullptr,
      Md, Vd, Hd);

  // final hidden
  tail_copy<<<dim3(8), dim3(256), 0, stream>>>(h, out + (size_t)Md * Vd);
}

// Round 3
// 1226.925 us; speedup vs baseline: 1.1352x; 1.0234x over previous
//
#include <hip/hip_runtime.h>
#include <hip/hip_bf16.h>
#include <cstdint>

using bf16 = __hip_bfloat16;
typedef __bf16 bf16x8 __attribute__((ext_vector_type(8)));
typedef float f32x4 __attribute__((ext_vector_type(4)));

constexpr int Hd = 512;
constexpr int Ld = 6;
constexpr int Fd = 2048;
constexpr int Vd = 50304;
constexpr int Md = 4096;  // B*S = 4*1024

// ---------- helpers ----------
__device__ __forceinline__ unsigned short f2b(float x) {
  return __builtin_bit_cast(unsigned short, __float2bfloat16(x));
}

__device__ __forceinline__ float gelu_tanh(float x) {
  const float c = 0.7978845608028654f;  // sqrt(2/pi)
  float x3 = x * x * x;
  return 0.5f * x * (1.0f + tanhf(c * (x + 0.044715f * x3)));
}

__device__ __forceinline__ void load16_lds(const bf16* g, bf16* l) {
  __builtin_amdgcn_global_load_lds(
      (const __attribute__((address_space(1))) void*)g,
      (__attribute__((address_space(3))) void*)l, 16, 0, 0);
}

// ---------- cast fp32 -> bf16, 8 elems/thread ----------
__global__ __launch_bounds__(256) void cast8(const float* __restrict__ in,
                                             bf16* __restrict__ out, int n8) {
  int i = blockIdx.x * 256 + threadIdx.x;
  if (i >= n8) return;
  const float4* p = (const float4*)in;
  float4 a = p[2 * i], b = p[2 * i + 1];
  uint4 o = {(unsigned)f2b(a.x) | ((unsigned)f2b(a.y) << 16),
             (unsigned)f2b(a.z) | ((unsigned)f2b(a.w) << 16),
             (unsigned)f2b(b.x) | ((unsigned)f2b(b.y) << 16),
             (unsigned)f2b(b.z) | ((unsigned)f2b(b.w) << 16)};
  ((uint4*)out)[i] = o;
}

// ---------- transpose+cast: in (R,C) f32 -> out (C,R) bf16, batched over z ----------
__global__ void transpose_cast(const float* __restrict__ in, bf16* __restrict__ out,
                               int R, int C) {
  __shared__ float tile[32][33];
  int l = blockIdx.z;
  in += (size_t)l * R * C;
  out += (size_t)l * R * C;
  int c0 = blockIdx.x * 32, r0 = blockIdx.y * 32;
#pragma unroll
  for (int i = 0; i < 4; i++) {
    int r = r0 + threadIdx.y + i * 8;
    tile[threadIdx.y + i * 8][threadIdx.x] = in[(size_t)r * C + c0 + threadIdx.x];
  }
  __syncthreads();
#pragma unroll
  for (int i = 0; i < 4; i++) {
    int c = c0 + threadIdx.y + i * 8;
    out[(size_t)c * R + r0 + threadIdx.x] = (bf16)tile[threadIdx.x][threadIdx.y + i * 8];
  }
}

// ---------- embedding gather ----------
__global__ void gather_embed(const int* __restrict__ ids, const float* __restrict__ emb,
                             float* __restrict__ h) {
  int row = blockIdx.x;
  int id = ids[row];
  const float4* src = (const float4*)(emb + (size_t)id * Hd);
  float4* dst = (float4*)(h + (size_t)row * Hd);
  dst[threadIdx.x] = src[threadIdx.x];
}

// ---------- layernorm, one wave per row, with fused split-K reduce ----------
// MODE 0: x = h[row]                         (plain LN)
// MODE 1: x = h + fb[col] + p0 + p1; h = x   (finish gemm2 split-K + residual)
// MODE 2: x = p0 + p1 + fb[col];    h = x    (finish hp split-K, overwrite)
template <int MODE>
__global__ __launch_bounds__(256) void ln_rows(
    const float* __restrict__ h, const float* __restrict__ p0,
    const float* __restrict__ p1, const float* __restrict__ fb,
    const float* __restrict__ w, const float* __restrict__ b,
    float* __restrict__ hout, bf16* __restrict__ y) {
  int row = blockIdx.x * 4 + (threadIdx.x >> 6);
  int lane = threadIdx.x & 63;
  size_t base = (size_t)row * Hd + lane * 8;
  float xv[8];
  if constexpr (MODE == 0) {
    *(float4*)&xv[0] = *(const float4*)(h + base);
    *(float4*)&xv[4] = *(const float4*)(h + base + 4);
  } else {
    float4 q0 = *(const float4*)(p0 + base), q1 = *(const float4*)(p0 + base + 4);
    float4 r0 = *(const float4*)(p1 + base), r1 = *(const float4*)(p1 + base + 4);
    float4 f0 = *(const float4*)(fb + lane * 8), f1 = *(const float4*)(fb + lane * 8 + 4);
    xv[0] = q0.x + r0.x + f0.x; xv[1] = q0.y + r0.y + f0.y;
    xv[2] = q0.z + r0.z + f0.z; xv[3] = q0.w + r0.w + f0.w;
    xv[4] = q1.x + r1.x + f1.x; xv[5] = q1.y + r1.y + f1.y;
    xv[6] = q1.z + r1.z + f1.z; xv[7] = q1.w + r1.w + f1.w;
    if constexpr (MODE == 1) {
      float4 a0 = *(const float4*)(h + base), a1 = *(const float4*)(h + base + 4);
      xv[0] += a0.x; xv[1] += a0.y; xv[2] += a0.z; xv[3] += a0.w;
      xv[4] += a1.x; xv[5] += a1.y; xv[6] += a1.z; xv[7] += a1.w;
    }
    *(float4*)(hout + base) = make_float4(xv[0], xv[1], xv[2], xv[3]);
    *(float4*)(hout + base + 4) = make_float4(xv[4], xv[5], xv[6], xv[7]);
  }
  float s = 0.f;
#pragma unroll
  for (int j = 0; j < 8; j++) s += xv[j];
#pragma unroll
  for (int off = 1; off < 64; off <<= 1) s += __shfl_xor(s, off);
  float mu = s * (1.0f / 512.0f);
  float s2 = 0.f;
#pragma unroll
  for (int j = 0; j < 8; j++) {
    xv[j] -= mu;
    s2 += xv[j] * xv[j];
  }
#pragma unroll
  for (int off = 1; off < 64; off <<= 1) s2 += __shfl_xor(s2, off);
  float scale = rsqrtf(s2 * (1.0f / 512.0f) + 1e-5f);
  float o[8];
#pragma unroll
  for (int j = 0; j < 8; j++) {
    float wj = w[lane * 8 + j], bj = b[lane * 8 + j];
    o[j] = xv[j] * scale * wj + bj;
  }
  uint4 pk = {(unsigned)f2b(o[0]) | ((unsigned)f2b(o[1]) << 16),
              (unsigned)f2b(o[2]) | ((unsigned)f2b(o[3]) << 16),
              (unsigned)f2b(o[4]) | ((unsigned)f2b(o[5]) << 16),
              (unsigned)f2b(o[6]) | ((unsigned)f2b(o[7]) << 16)};
  *(uint4*)(y + base) = pk;
}

// ---------- finish split-K gemm2 of stack1: h += fb + p0 + p1, also emit bf16 ----------
__global__ __launch_bounds__(256) void finish2(
    const float* __restrict__ p0, const float* __restrict__ p1,
    const float* __restrict__ fb, float* __restrict__ h, bf16* __restrict__ hbf) {
  int i = blockIdx.x * 256 + threadIdx.x;  // 8 elems each; grid covers 2M elems
  size_t base = (size_t)i * 8;
  int col = (int)(base & 511);
  float x[8];
#pragma unroll
  for (int j = 0; j < 8; j += 4) {
    float4 a = *(const float4*)(h + base + j);
    float4 q = *(const float4*)(p0 + base + j);
    float4 r = *(const float4*)(p1 + base + j);
    float4 f = *(const float4*)(fb + col + j);
    x[j] = a.x + q.x + r.x + f.x; x[j + 1] = a.y + q.y + r.y + f.y;
    x[j + 2] = a.z + q.z + r.z + f.z; x[j + 3] = a.w + q.w + r.w + f.w;
    *(float4*)(h + base + j) = make_float4(x[j], x[j + 1], x[j + 2], x[j + 3]);
  }
  uint4 pk = {(unsigned)f2b(x[0]) | ((unsigned)f2b(x[1]) << 16),
              (unsigned)f2b(x[2]) | ((unsigned)f2b(x[3]) << 16),
              (unsigned)f2b(x[4]) | ((unsigned)f2b(x[5]) << 16),
              (unsigned)f2b(x[6]) | ((unsigned)f2b(x[7]) << 16)};
  *(uint4*)(hbf + base) = pk;
}

// ---------- GEMM: C(M,N) = A(M,:) @ Bt(N,:)^T over k0..k0+Klen, bf16 in ----------
// Tile 128 x BN, BK=32.  k0 = blockIdx.z * Klen (split-K).
// EPI 0: out_bf16 = gelu(acc + bias)
// EPI 3: out_f32  = acc                         (logits; MSWZ grid)
// EPI 4: out_f32[z*M*N + idx] = acc             (split-K partial)
template <int EPI, int BN, bool MSWZ>
__global__ __launch_bounds__(256) void gemm_bt(
    const bf16* __restrict__ A, const bf16* __restrict__ Bt,
    const float* __restrict__ bias, float* __restrict__ outF,
    bf16* __restrict__ outB, int M, int N, int Klen, int lda, int ldb) {
  __shared__ bf16 lds[128 * 32 + BN * 32];
  bf16* ldsA = lds;
  bf16* ldsB = lds + 128 * 32;
  const int tid = threadIdx.x;
  const int wave = tid >> 6;
  const int lane = tid & 63;
  constexpr int NF = BN / 32;
  const int wm = (wave >> 1) * 64;
  const int wn = (wave & 1) * (BN / 2);

  int bm, bn;
  if constexpr (MSWZ) {
    // bijective XCD swizzle over 1-D grid (gridDim.x % 8 == 0), M-panel inner
    const int per = gridDim.x >> 3;
    const int wg = (blockIdx.x & 7) * per + (blockIdx.x >> 3);
    const int nM = M >> 7;
    bm = wg & (nM - 1);
    bn = wg / nM;
  } else {
    bn = blockIdx.x;
    bm = blockIdx.y;
  }
  const int rowA0 = bm * 128;
  const int rowB0 = bn * BN;
  const int k0 = blockIdx.z * Klen;

  f32x4 acc[4][NF];
#pragma unroll
  for (int i = 0; i < 4; i++)
#pragma unroll
    for (int j = 0; j < NF; j++) acc[i][j] = (f32x4){0.f, 0.f, 0.f, 0.f};

  const int fr = lane & 15;
  const int ko = (lane >> 4) * 8;

  for (int kt = 0; kt < Klen; kt += 32) {
#pragma unroll
    for (int r = 0; r < 2; r++) {
      const int base = r * 4 + wave;
      const int c = base * 64 + lane;
      const int row = c >> 2, cw = c & 3;
      load16_lds(A + (size_t)(rowA0 + row) * lda + k0 + kt + cw * 8,
                 ldsA + (size_t)base * 512);
    }
#pragma unroll
    for (int r = 0; r < BN / 64; r++) {
      const int base = r * 4 + wave;
      const int c = base * 64 + lane;
      const int row = c >> 2, cw = c & 3;
      load16_lds(Bt + (size_t)(rowB0 + row) * ldb + k0 + kt + cw * 8,
                 ldsB + (size_t)base * 512);
    }
    __syncthreads();
    bf16x8 af[4], bfr[NF];
#pragma unroll
    for (int f = 0; f < 4; f++)
      af[f] = *(const bf16x8*)(ldsA + (wm + f * 16 + fr) * 32 + ko);
#pragma unroll
    for (int f = 0; f < NF; f++)
      bfr[f] = *(const bf16x8*)(ldsB + (wn + f * 16 + fr) * 32 + ko);
#pragma unroll
    for (int i = 0; i < 4; i++)
#pragma unroll
      for (int j = 0; j < NF; j++)
        acc[i][j] = __builtin_amdgcn_mfma_f32_16x16x32_bf16(af[i], bfr[j], acc[i][j], 0, 0, 0);
    __syncthreads();
  }

  if constexpr (EPI == 4) outF += (size_t)blockIdx.z * M * N;
  const int orow = (lane >> 4) * 4;
  const int ocol = lane & 15;
#pragma unroll
  for (int i = 0; i < 4; i++) {
#pragma unroll
    for (int j = 0; j < NF; j++) {
      int row0 = rowA0 + wm + i * 16 + orow;
      int col = rowB0 + wn + j * 16 + ocol;
#pragma unroll
      for (int q = 0; q < 4; q++) {
        float v = acc[i][j][q];
        size_t idx = (size_t)(row0 + q) * N + col;
        if constexpr (EPI == 0) {
          outB[idx] = (bf16)gelu_tanh(v + bias[col]);
        } else {
          outF[idx] = v;
        }
      }
    }
  }
}

// ---------- final hidden: h[:, -1, :] -> out ----------
__global__ void tail_copy(const float* __restrict__ h, float* __restrict__ out) {
  int t = blockIdx.x * 256 + threadIdx.x;  // 0..2047
  int b = t >> 9, k = t & 511;
  out[t] = h[((size_t)(b * 1024 + 1023)) * Hd + k];
}

// ---------- launch ----------
extern "C" void kernel_launch(void* const* d_in, const int* in_sizes, int n_in,
                              void* d_out, int out_size, void* d_ws, size_t ws_size,
                              hipStream_t stream) {
  const int* ids = (const int*)d_in[0];
  const float* emb = (const float*)d_in[1];
  const float* hp_w = (const float*)d_in[2];
  const float* hp_b = (const float*)d_in[3];
  const float* ln_w = (const float*)d_in[4];
  const float* ln_b = (const float*)d_in[5];
  const float* W1 = (const float*)d_in[6];
  const float* b1 = (const float*)d_in[7];
  const float* W2 = (const float*)d_in[8];
  const float* b2 = (const float*)d_in[9];
  const float* lnf_w = (const float*)d_in[10];
  const float* lnf_b = (const float*)d_in[11];
  const float* eow = (const float*)d_in[12];
  float* out = (float*)d_out;

  char* ws = (char*)d_ws;
  float* h = (float*)(ws);                          // 8 MB
  bf16* ybf = (bf16*)(ws + (8u << 20));             // 4 MB (LN out / hbf for hp)
  bf16* abf = (bf16*)(ws + (12u << 20));            // 16 MB (gelu activations)
  bf16* W1t = (bf16*)(ws + (28u << 20));            // 12 MB
  bf16* W2t = (bf16*)(ws + (40u << 20));            // 12 MB
  bf16* hpwB = (bf16*)(ws + (52u << 20));           // 0.5 MB
  bf16* eowB = (bf16*)(ws + (53u << 20));           // 51.5 MB

  // split-K partials live in d_out's logits region (overwritten by logits GEMM later)
  float* p0 = out;                    // 8 MB worth (2M floats)
  float* p1 = out + (size_t)Md * Hd;  // next 2M floats

  // weight prep (bf16 cast; W1/W2 transposed to (N,K))
  cast8<<<dim3(Vd * Hd / 8 / 256), dim3(256), 0, stream>>>(eow, eowB, Vd * Hd / 8);
  cast8<<<dim3(Hd * Hd / 8 / 256), dim3(256), 0, stream>>>(hp_w, hpwB, Hd * Hd / 8);
  transpose_cast<<<dim3(Fd / 32, Hd / 32, Ld), dim3(32, 8), 0, stream>>>(W1, W1t, Hd, Fd);
  transpose_cast<<<dim3(Hd / 32, Fd / 32, Ld), dim3(32, 8), 0, stream>>>(W2, W2t, Fd, Hd);

  gather_embed<<<dim3(Md), dim3(128), 0, stream>>>(ids, emb, h);

  // one MLP layer: ln (with optional fused finish) -> gemm1 -> split-K gemm2
  auto layer = [&](int l, int mode, const float* fb, const float* lw, const float* lb) {
    if (mode == 0)
      ln_rows<0><<<dim3(Md / 4), dim3(256), 0, stream>>>(h, p0, p1, fb, lw, lb, h, ybf);
    else if (mode == 1)
      ln_rows<1><<<dim3(Md / 4), dim3(256), 0, stream>>>(h, p0, p1, fb, lw, lb, h, ybf);
    else
      ln_rows<2><<<dim3(Md / 4), dim3(256), 0, stream>>>(h, p0, p1, fb, lw, lb, h, ybf);
    gemm_bt<0, 128, false><<<dim3(Fd / 128, Md / 128), dim3(256), 0, stream>>>(
        ybf, W1t + (size_t)l * Fd * Hd, b1 + (size_t)l * Fd, (float*)nullptr, abf,
        Md, Fd, Hd, Hd, Hd);
    gemm_bt<4, 64, false><<<dim3(Hd / 64, Md / 128, 2), dim3(256), 0, stream>>>(
        abf, W2t + (size_t)l * Hd * Fd, (const float*)nullptr, p0, (bf16*)nullptr,
        Md, Hd, Fd / 2, Fd, Fd);
  };

  // ---- stack 1 ----
  layer(0, 0, nullptr, ln_w, ln_b);
  for (int l = 1; l < Ld; l++)
    layer(l, 1, b2 + (size_t)(l - 1) * Hd, ln_w + (size_t)l * Hd, ln_b + (size_t)l * Hd);
  // finish layer 5 + emit bf16 for hp
  finish2<<<dim3(Md * Hd / 8 / 256), dim3(256), 0, stream>>>(
      p0, p1, b2 + (size_t)(Ld - 1) * Hd, h, ybf);

  // ---- hp projection: h @ hp_w^T + hp_b (split-K=2, finish fused into next LN) ----
  gemm_bt<4, 64, false><<<dim3(Hd / 64, Md / 128, 2), dim3(256), 0, stream>>>(
      ybf, hpwB, (const float*)nullptr, p0, (bf16*)nullptr, Md, Hd, Hd / 2, Hd, Hd);

  // ---- stack 2 ----
  layer(0, 2, hp_b, ln_w, ln_b);
  for (int l = 1; l < Ld; l++)
    layer(l, 1, b2 + (size_t)(l - 1) * Hd, ln_w + (size_t)l * Hd, ln_b + (size_t)l * Hd);

  // ---- final LN (fused finish of last gemm2) + logits ----
  ln_rows<1><<<dim3(Md / 4), dim3(256), 0, stream>>>(
      h, p0, p1, b2 + (size_t)(Ld - 1) * Hd, lnf_w, lnf_b, h, ybf);
  gemm_bt<3, 128, true><<<dim3((Vd / 128) * (Md / 128)), dim3(256), 0, stream>>>(
      ybf, eowB, (const float*)nullptr, out, (bf16*)nullptr, Md, Vd, Hd, Hd, Hd);

  // final hidden
  tail_copy<<<dim3(8), dim3(256), 0, stream>>>(h, out + (size_t)Md * Vd);
}

// Round 4
// 1098.979 us; speedup vs baseline: 1.2674x; 1.1164x over previous
//
#include <hip/hip_runtime.h>
#include <hip/hip_bf16.h>
#include <cstdint>

using bf16 = __hip_bfloat16;
typedef __bf16 bf16x8 __attribute__((ext_vector_type(8)));
typedef float f32x4 __attribute__((ext_vector_type(4)));

constexpr int Hd = 512;
constexpr int Ld = 6;
constexpr int Fd = 2048;
constexpr int Vd = 50304;
constexpr int Md = 4096;  // B*S = 4*1024

// ---------- helpers ----------
__device__ __forceinline__ unsigned short f2b(float x) {
  return __builtin_bit_cast(unsigned short, __float2bfloat16(x));
}

__device__ __forceinline__ float gelu_tanh(float x) {
  const float c = 0.7978845608028654f;  // sqrt(2/pi)
  float x3 = x * x * x;
  return 0.5f * x * (1.0f + tanhf(c * (x + 0.044715f * x3)));
}

__device__ __forceinline__ void load16_lds(const bf16* g, bf16* l) {
  __builtin_amdgcn_global_load_lds(
      (const __attribute__((address_space(1))) void*)g,
      (__attribute__((address_space(3))) void*)l, 16, 0, 0);
}

// ---------- cast fp32 -> bf16, 8 elems/thread ----------
__global__ __launch_bounds__(256) void cast8(const float* __restrict__ in,
                                             bf16* __restrict__ out, int n8) {
  int i = blockIdx.x * 256 + threadIdx.x;
  if (i >= n8) return;
  const float4* p = (const float4*)in;
  float4 a = p[2 * i], b = p[2 * i + 1];
  uint4 o = {(unsigned)f2b(a.x) | ((unsigned)f2b(a.y) << 16),
             (unsigned)f2b(a.z) | ((unsigned)f2b(a.w) << 16),
             (unsigned)f2b(b.x) | ((unsigned)f2b(b.y) << 16),
             (unsigned)f2b(b.z) | ((unsigned)f2b(b.w) << 16)};
  ((uint4*)out)[i] = o;
}

// ---------- transpose+cast: in (R,C) f32 -> out (C,R) bf16, batched over z ----------
__global__ void transpose_cast(const float* __restrict__ in, bf16* __restrict__ out,
                               int R, int C) {
  __shared__ float tile[32][33];
  int l = blockIdx.z;
  in += (size_t)l * R * C;
  out += (size_t)l * R * C;
  int c0 = blockIdx.x * 32, r0 = blockIdx.y * 32;
#pragma unroll
  for (int i = 0; i < 4; i++) {
    int r = r0 + threadIdx.y + i * 8;
    tile[threadIdx.y + i * 8][threadIdx.x] = in[(size_t)r * C + c0 + threadIdx.x];
  }
  __syncthreads();
#pragma unroll
  for (int i = 0; i < 4; i++) {
    int c = c0 + threadIdx.y + i * 8;
    out[(size_t)c * R + r0 + threadIdx.x] = (bf16)tile[threadIdx.x][threadIdx.y + i * 8];
  }
}

// ---------- embedding gather ----------
__global__ void gather_embed(const int* __restrict__ ids, const float* __restrict__ emb,
                             float* __restrict__ h) {
  int row = blockIdx.x;
  int id = ids[row];
  const float4* src = (const float4*)(emb + (size_t)id * Hd);
  float4* dst = (float4*)(h + (size_t)row * Hd);
  dst[threadIdx.x] = src[threadIdx.x];
}

// ---------- layernorm, one wave per row, with fused split-K reduce ----------
// MODE 0: x = h[row]                         (plain LN)
// MODE 1: x = h + fb[col] + p0 + p1; h = x   (finish gemm2 split-K + residual)
// MODE 2: x = p0 + p1 + fb[col];    h = x    (finish hp split-K, overwrite)
template <int MODE>
__global__ __launch_bounds__(256) void ln_rows(
    const float* __restrict__ h, const float* __restrict__ p0,
    const float* __restrict__ p1, const float* __restrict__ fb,
    const float* __restrict__ w, const float* __restrict__ b,
    float* __restrict__ hout, bf16* __restrict__ y) {
  int row = blockIdx.x * 4 + (threadIdx.x >> 6);
  int lane = threadIdx.x & 63;
  size_t base = (size_t)row * Hd + lane * 8;
  float xv[8];
  if constexpr (MODE == 0) {
    *(float4*)&xv[0] = *(const float4*)(h + base);
    *(float4*)&xv[4] = *(const float4*)(h + base + 4);
  } else {
    float4 q0 = *(const float4*)(p0 + base), q1 = *(const float4*)(p0 + base + 4);
    float4 r0 = *(const float4*)(p1 + base), r1 = *(const float4*)(p1 + base + 4);
    float4 f0 = *(const float4*)(fb + lane * 8), f1 = *(const float4*)(fb + lane * 8 + 4);
    xv[0] = q0.x + r0.x + f0.x; xv[1] = q0.y + r0.y + f0.y;
    xv[2] = q0.z + r0.z + f0.z; xv[3] = q0.w + r0.w + f0.w;
    xv[4] = q1.x + r1.x + f1.x; xv[5] = q1.y + r1.y + f1.y;
    xv[6] = q1.z + r1.z + f1.z; xv[7] = q1.w + r1.w + f1.w;
    if constexpr (MODE == 1) {
      float4 a0 = *(const float4*)(h + base), a1 = *(const float4*)(h + base + 4);
      xv[0] += a0.x; xv[1] += a0.y; xv[2] += a0.z; xv[3] += a0.w;
      xv[4] += a1.x; xv[5] += a1.y; xv[6] += a1.z; xv[7] += a1.w;
    }
    *(float4*)(hout + base) = make_float4(xv[0], xv[1], xv[2], xv[3]);
    *(float4*)(hout + base + 4) = make_float4(xv[4], xv[5], xv[6], xv[7]);
  }
  float s = 0.f;
#pragma unroll
  for (int j = 0; j < 8; j++) s += xv[j];
#pragma unroll
  for (int off = 1; off < 64; off <<= 1) s += __shfl_xor(s, off);
  float mu = s * (1.0f / 512.0f);
  float s2 = 0.f;
#pragma unroll
  for (int j = 0; j < 8; j++) {
    xv[j] -= mu;
    s2 += xv[j] * xv[j];
  }
#pragma unroll
  for (int off = 1; off < 64; off <<= 1) s2 += __shfl_xor(s2, off);
  float scale = rsqrtf(s2 * (1.0f / 512.0f) + 1e-5f);
  float o[8];
#pragma unroll
  for (int j = 0; j < 8; j++) {
    float wj = w[lane * 8 + j], bj = b[lane * 8 + j];
    o[j] = xv[j] * scale * wj + bj;
  }
  uint4 pk = {(unsigned)f2b(o[0]) | ((unsigned)f2b(o[1]) << 16),
              (unsigned)f2b(o[2]) | ((unsigned)f2b(o[3]) << 16),
              (unsigned)f2b(o[4]) | ((unsigned)f2b(o[5]) << 16),
              (unsigned)f2b(o[6]) | ((unsigned)f2b(o[7]) << 16)};
  *(uint4*)(y + base) = pk;
}

// ---------- finish split-K gemm2 of stack1: h += fb + p0 + p1, also emit bf16 ----------
__global__ __launch_bounds__(256) void finish2(
    const float* __restrict__ p0, const float* __restrict__ p1,
    const float* __restrict__ fb, float* __restrict__ h, bf16* __restrict__ hbf) {
  int i = blockIdx.x * 256 + threadIdx.x;  // 8 elems each; grid covers 2M elems
  size_t base = (size_t)i * 8;
  int col = (int)(base & 511);
  float x[8];
#pragma unroll
  for (int j = 0; j < 8; j += 4) {
    float4 a = *(const float4*)(h + base + j);
    float4 q = *(const float4*)(p0 + base + j);
    float4 r = *(const float4*)(p1 + base + j);
    float4 f = *(const float4*)(fb + col + j);
    x[j] = a.x + q.x + r.x + f.x; x[j + 1] = a.y + q.y + r.y + f.y;
    x[j + 2] = a.z + q.z + r.z + f.z; x[j + 3] = a.w + q.w + r.w + f.w;
    *(float4*)(h + base + j) = make_float4(x[j], x[j + 1], x[j + 2], x[j + 3]);
  }
  uint4 pk = {(unsigned)f2b(x[0]) | ((unsigned)f2b(x[1]) << 16),
              (unsigned)f2b(x[2]) | ((unsigned)f2b(x[3]) << 16),
              (unsigned)f2b(x[4]) | ((unsigned)f2b(x[5]) << 16),
              (unsigned)f2b(x[6]) | ((unsigned)f2b(x[7]) << 16)};
  *(uint4*)(hbf + base) = pk;
}

// ---------- GEMM: C(M,N) = A(M,:) @ Bt(N,:)^T over k0..k0+Klen, bf16 in ----------
// Tile 128 x BN, BK=32, 2-phase double-buffered LDS (T3-minimum schedule).
// EPI 0: out_bf16 = gelu(acc + bias)
// EPI 3: out_f32  = acc                         (logits; MSWZ grid)
// EPI 4: out_f32[z*M*N + idx] = acc             (split-K partial)
template <int EPI, int BN, bool MSWZ>
__global__ __launch_bounds__(256) void gemm_bt(
    const bf16* __restrict__ A, const bf16* __restrict__ Bt,
    const float* __restrict__ bias, float* __restrict__ outF,
    bf16* __restrict__ outB, int M, int N, int Klen, int lda, int ldb) {
  constexpr int ASZ = 128 * 32;
  constexpr int BSZ = BN * 32;
  constexpr int TILE = ASZ + BSZ;
  __shared__ bf16 lds[2 * TILE];
  const int tid = threadIdx.x;
  const int wave = tid >> 6;
  const int lane = tid & 63;
  constexpr int NF = BN / 32;
  const int wm = (wave >> 1) * 64;
  const int wn = (wave & 1) * (BN / 2);

  int bm, bn;
  if constexpr (MSWZ) {
    // bijective XCD swizzle over 1-D grid (gridDim.x % 8 == 0), M-panel inner
    const int per = gridDim.x >> 3;
    const int wg = (blockIdx.x & 7) * per + (blockIdx.x >> 3);
    const int nM = M >> 7;
    bm = wg & (nM - 1);
    bn = wg / nM;
  } else {
    bn = blockIdx.x;
    bm = blockIdx.y;
  }
  const int rowA0 = bm * 128;
  const int rowB0 = bn * BN;
  const int k0 = blockIdx.z * Klen;

  // per-thread staging source pointers (advance +32 elems per K-step)
  const bf16* srcA[2];
#pragma unroll
  for (int r = 0; r < 2; r++) {
    int c = (r * 4 + wave) * 64 + lane;
    srcA[r] = A + (size_t)(rowA0 + (c >> 2)) * lda + k0 + (c & 3) * 8;
  }
  const bf16* srcB[BN / 64];
#pragma unroll
  for (int r = 0; r < BN / 64; r++) {
    int c = (r * 4 + wave) * 64 + lane;
    srcB[r] = Bt + (size_t)(rowB0 + (c >> 2)) * ldb + k0 + (c & 3) * 8;
  }

  f32x4 acc[4][NF];
#pragma unroll
  for (int i = 0; i < 4; i++)
#pragma unroll
    for (int j = 0; j < NF; j++) acc[i][j] = (f32x4){0.f, 0.f, 0.f, 0.f};

  const int fr = lane & 15;
  const int ko = (lane >> 4) * 8;

  auto STAGE = [&](int buf) {
    bf16* dst = lds + buf * TILE;
#pragma unroll
    for (int r = 0; r < 2; r++) {
      load16_lds(srcA[r], dst + (r * 4 + wave) * 512);
      srcA[r] += 32;
    }
#pragma unroll
    for (int r = 0; r < BN / 64; r++) {
      load16_lds(srcB[r], dst + ASZ + (r * 4 + wave) * 512);
      srcB[r] += 32;
    }
  };

  STAGE(0);
  __syncthreads();
  const int nIter = Klen >> 5;
  for (int it = 0; it < nIter; ++it) {
    const int cur = it & 1;
    if (it + 1 < nIter) STAGE(cur ^ 1);  // prefetch next tile into other buffer
    const bf16* lA = lds + cur * TILE;
    const bf16* lB = lA + ASZ;
    bf16x8 af[4], bfr[NF];
#pragma unroll
    for (int f = 0; f < 4; f++)
      af[f] = *(const bf16x8*)(lA + (wm + f * 16 + fr) * 32 + ko);
#pragma unroll
    for (int f = 0; f < NF; f++)
      bfr[f] = *(const bf16x8*)(lB + (wn + f * 16 + fr) * 32 + ko);
#pragma unroll
    for (int i = 0; i < 4; i++)
#pragma unroll
      for (int j = 0; j < NF; j++)
        acc[i][j] = __builtin_amdgcn_mfma_f32_16x16x32_bf16(af[i], bfr[j], acc[i][j], 0, 0, 0);
    __syncthreads();  // drains this iter's STAGE (vmcnt) + guards buf reuse
  }

  if constexpr (EPI == 4) outF += (size_t)blockIdx.z * M * N;
  const int orow = (lane >> 4) * 4;
  const int ocol = lane & 15;
#pragma unroll
  for (int i = 0; i < 4; i++) {
#pragma unroll
    for (int j = 0; j < NF; j++) {
      int row0 = rowA0 + wm + i * 16 + orow;
      int col = rowB0 + wn + j * 16 + ocol;
#pragma unroll
      for (int q = 0; q < 4; q++) {
        float v = acc[i][j][q];
        size_t idx = (size_t)(row0 + q) * N + col;
        if constexpr (EPI == 0) {
          outB[idx] = (bf16)gelu_tanh(v + bias[col]);
        } else {
          outF[idx] = v;
        }
      }
    }
  }
}

// ---------- final hidden: h[:, -1, :] -> out ----------
__global__ void tail_copy(const float* __restrict__ h, float* __restrict__ out) {
  int t = blockIdx.x * 256 + threadIdx.x;  // 0..2047
  int b = t >> 9, k = t & 511;
  out[t] = h[((size_t)(b * 1024 + 1023)) * Hd + k];
}

// ---------- launch ----------
extern "C" void kernel_launch(void* const* d_in, const int* in_sizes, int n_in,
                              void* d_out, int out_size, void* d_ws, size_t ws_size,
                              hipStream_t stream) {
  const int* ids = (const int*)d_in[0];
  const float* emb = (const float*)d_in[1];
  const float* hp_w = (const float*)d_in[2];
  const float* hp_b = (const float*)d_in[3];
  const float* ln_w = (const float*)d_in[4];
  const float* ln_b = (const float*)d_in[5];
  const float* W1 = (const float*)d_in[6];
  const float* b1 = (const float*)d_in[7];
  const float* W2 = (const float*)d_in[8];
  const float* b2 = (const float*)d_in[9];
  const float* lnf_w = (const float*)d_in[10];
  const float* lnf_b = (const float*)d_in[11];
  const float* eow = (const float*)d_in[12];
  float* out = (float*)d_out;

  char* ws = (char*)d_ws;
  float* h = (float*)(ws);                          // 8 MB
  bf16* ybf = (bf16*)(ws + (8u << 20));             // 4 MB (LN out / hbf for hp)
  bf16* abf = (bf16*)(ws + (12u << 20));            // 16 MB (gelu activations)
  bf16* W1t = (bf16*)(ws + (28u << 20));            // 12 MB
  bf16* W2t = (bf16*)(ws + (40u << 20));            // 12 MB
  bf16* hpwB = (bf16*)(ws + (52u << 20));           // 0.5 MB
  bf16* eowB = (bf16*)(ws + (53u << 20));           // 51.5 MB

  // split-K partials live in d_out's logits region (overwritten by logits GEMM later)
  float* p0 = out;                    // 8 MB worth (2M floats)
  float* p1 = out + (size_t)Md * Hd;  // next 2M floats

  // weight prep (bf16 cast; W1/W2 transposed to (N,K))
  cast8<<<dim3(Vd * Hd / 8 / 256), dim3(256), 0, stream>>>(eow, eowB, Vd * Hd / 8);
  cast8<<<dim3(Hd * Hd / 8 / 256), dim3(256), 0, stream>>>(hp_w, hpwB, Hd * Hd / 8);
  transpose_cast<<<dim3(Fd / 32, Hd / 32, Ld), dim3(32, 8), 0, stream>>>(W1, W1t, Hd, Fd);
  transpose_cast<<<dim3(Hd / 32, Fd / 32, Ld), dim3(32, 8), 0, stream>>>(W2, W2t, Fd, Hd);

  gather_embed<<<dim3(Md), dim3(128), 0, stream>>>(ids, emb, h);

  // one MLP layer: ln (with optional fused finish) -> gemm1 -> split-K gemm2
  auto layer = [&](int l, int mode, const float* fb, const float* lw, const float* lb) {
    if (mode == 0)
      ln_rows<0><<<dim3(Md / 4), dim3(256), 0, stream>>>(h, p0, p1, fb, lw, lb, h, ybf);
    else if (mode == 1)
      ln_rows<1><<<dim3(Md / 4), dim3(256), 0, stream>>>(h, p0, p1, fb, lw, lb, h, ybf);
    else
      ln_rows<2><<<dim3(Md / 4), dim3(256), 0, stream>>>(h, p0, p1, fb, lw, lb, h, ybf);
    gemm_bt<0, 128, false><<<dim3(Fd / 128, Md / 128), dim3(256), 0, stream>>>(
        ybf, W1t + (size_t)l * Fd * Hd, b1 + (size_t)l * Fd, (float*)nullptr, abf,
        Md, Fd, Hd, Hd, Hd);
    gemm_bt<4, 64, false><<<dim3(Hd / 64, Md / 128, 2), dim3(256), 0, stream>>>(
        abf, W2t + (size_t)l * Hd * Fd, (const float*)nullptr, p0, (bf16*)nullptr,
        Md, Hd, Fd / 2, Fd, Fd);
  };

  // ---- stack 1 ----
  layer(0, 0, nullptr, ln_w, ln_b);
  for (int l = 1; l < Ld; l++)
    layer(l, 1, b2 + (size_t)(l - 1) * Hd, ln_w + (size_t)l * Hd, ln_b + (size_t)l * Hd);
  // finish layer 5 + emit bf16 for hp
  finish2<<<dim3(Md * Hd / 8 / 256), dim3(256), 0, stream>>>(
      p0, p1, b2 + (size_t)(Ld - 1) * Hd, h, ybf);

  // ---- hp projection: h @ hp_w^T + hp_b (split-K=2, finish fused into next LN) ----
  gemm_bt<4, 64, false><<<dim3(Hd / 64, Md / 128, 2), dim3(256), 0, stream>>>(
      ybf, hpwB, (const float*)nullptr, p0, (bf16*)nullptr, Md, Hd, Hd / 2, Hd, Hd);

  // ---- stack 2 ----
  layer(0, 2, hp_b, ln_w, ln_b);
  for (int l = 1; l < Ld; l++)
    layer(l, 1, b2 + (size_t)(l - 1) * Hd, ln_w + (size_t)l * Hd, ln_b + (size_t)l * Hd);

  // ---- final LN (fused finish of last gemm2) + logits ----
  ln_rows<1><<<dim3(Md / 4), dim3(256), 0, stream>>>(
      h, p0, p1, b2 + (size_t)(Ld - 1) * Hd, lnf_w, lnf_b, h, ybf);
  gemm_bt<3, 128, true><<<dim3((Vd / 128) * (Md / 128)), dim3(256), 0, stream>>>(
      ybf, eowB, (const float*)nullptr, out, (bf16*)nullptr, Md, Vd, Hd, Hd, Hd);

  // final hidden
  tail_copy<<<dim3(8), dim3(256), 0, stream>>>(h, out + (size_t)Md * Vd);
}

// Round 5
// 1091.828 us; speedup vs baseline: 1.2757x; 1.0065x over previous
//
#include <hip/hip_runtime.h>
#include <hip/hip_bf16.h>
#include <cstdint>

using bf16 = __hip_bfloat16;
typedef __bf16 bf16x8 __attribute__((ext_vector_type(8)));
typedef float f32x4 __attribute__((ext_vector_type(4)));

constexpr int Hd = 512;
constexpr int Ld = 6;
constexpr int Fd = 2048;
constexpr int Vd = 50304;
constexpr int Md = 4096;  // B*S = 4*1024

// ---------- helpers ----------
__device__ __forceinline__ unsigned short f2b(float x) {
  return __builtin_bit_cast(unsigned short, __float2bfloat16(x));
}

__device__ __forceinline__ float gelu_tanh(float x) {
  const float c = 0.7978845608028654f;  // sqrt(2/pi)
  float x3 = x * x * x;
  return 0.5f * x * (1.0f + tanhf(c * (x + 0.044715f * x3)));
}

__device__ __forceinline__ void load16_lds(const bf16* g, bf16* l) {
  __builtin_amdgcn_global_load_lds(
      (const __attribute__((address_space(1))) void*)g,
      (__attribute__((address_space(3))) void*)l, 16, 0, 0);
}

// ---------- cast fp32 -> bf16, 8 elems/thread ----------
__global__ __launch_bounds__(256) void cast8(const float* __restrict__ in,
                                             bf16* __restrict__ out, int n8) {
  int i = blockIdx.x * 256 + threadIdx.x;
  if (i >= n8) return;
  const float4* p = (const float4*)in;
  float4 a = p[2 * i], b = p[2 * i + 1];
  uint4 o = {(unsigned)f2b(a.x) | ((unsigned)f2b(a.y) << 16),
             (unsigned)f2b(a.z) | ((unsigned)f2b(a.w) << 16),
             (unsigned)f2b(b.x) | ((unsigned)f2b(b.y) << 16),
             (unsigned)f2b(b.z) | ((unsigned)f2b(b.w) << 16)};
  ((uint4*)out)[i] = o;
}

// ---------- transpose+cast: in (R,C) f32 -> out (C,R) bf16, batched over z ----------
__global__ void transpose_cast(const float* __restrict__ in, bf16* __restrict__ out,
                               int R, int C) {
  __shared__ float tile[32][33];
  int l = blockIdx.z;
  in += (size_t)l * R * C;
  out += (size_t)l * R * C;
  int c0 = blockIdx.x * 32, r0 = blockIdx.y * 32;
#pragma unroll
  for (int i = 0; i < 4; i++) {
    int r = r0 + threadIdx.y + i * 8;
    tile[threadIdx.y + i * 8][threadIdx.x] = in[(size_t)r * C + c0 + threadIdx.x];
  }
  __syncthreads();
#pragma unroll
  for (int i = 0; i < 4; i++) {
    int c = c0 + threadIdx.y + i * 8;
    out[(size_t)c * R + r0 + threadIdx.x] = (bf16)tile[threadIdx.x][threadIdx.y + i * 8];
  }
}

// ---------- embedding gather ----------
__global__ void gather_embed(const int* __restrict__ ids, const float* __restrict__ emb,
                             float* __restrict__ h) {
  int row = blockIdx.x;
  int id = ids[row];
  const float4* src = (const float4*)(emb + (size_t)id * Hd);
  float4* dst = (float4*)(h + (size_t)row * Hd);
  dst[threadIdx.x] = src[threadIdx.x];
}

// ---------- layernorm, one wave per row, with fused split-K reduce ----------
// MODE 0: x = h[row]                         (plain LN)
// MODE 1: x = h + fb[col] + p0 + p1; h = x   (finish gemm2 split-K + residual)
// MODE 2: x = p0 + p1 + fb[col];    h = x    (finish hp split-K, overwrite)
template <int MODE>
__global__ __launch_bounds__(256) void ln_rows(
    const float* __restrict__ h, const float* __restrict__ p0,
    const float* __restrict__ p1, const float* __restrict__ fb,
    const float* __restrict__ w, const float* __restrict__ b,
    float* __restrict__ hout, bf16* __restrict__ y) {
  int row = blockIdx.x * 4 + (threadIdx.x >> 6);
  int lane = threadIdx.x & 63;
  size_t base = (size_t)row * Hd + lane * 8;
  float xv[8];
  if constexpr (MODE == 0) {
    *(float4*)&xv[0] = *(const float4*)(h + base);
    *(float4*)&xv[4] = *(const float4*)(h + base + 4);
  } else {
    float4 q0 = *(const float4*)(p0 + base), q1 = *(const float4*)(p0 + base + 4);
    float4 r0 = *(const float4*)(p1 + base), r1 = *(const float4*)(p1 + base + 4);
    float4 f0 = *(const float4*)(fb + lane * 8), f1 = *(const float4*)(fb + lane * 8 + 4);
    xv[0] = q0.x + r0.x + f0.x; xv[1] = q0.y + r0.y + f0.y;
    xv[2] = q0.z + r0.z + f0.z; xv[3] = q0.w + r0.w + f0.w;
    xv[4] = q1.x + r1.x + f1.x; xv[5] = q1.y + r1.y + f1.y;
    xv[6] = q1.z + r1.z + f1.z; xv[7] = q1.w + r1.w + f1.w;
    if constexpr (MODE == 1) {
      float4 a0 = *(const float4*)(h + base), a1 = *(const float4*)(h + base + 4);
      xv[0] += a0.x; xv[1] += a0.y; xv[2] += a0.z; xv[3] += a0.w;
      xv[4] += a1.x; xv[5] += a1.y; xv[6] += a1.z; xv[7] += a1.w;
    }
    *(float4*)(hout + base) = make_float4(xv[0], xv[1], xv[2], xv[3]);
    *(float4*)(hout + base + 4) = make_float4(xv[4], xv[5], xv[6], xv[7]);
  }
  float s = 0.f;
#pragma unroll
  for (int j = 0; j < 8; j++) s += xv[j];
#pragma unroll
  for (int off = 1; off < 64; off <<= 1) s += __shfl_xor(s, off);
  float mu = s * (1.0f / 512.0f);
  float s2 = 0.f;
#pragma unroll
  for (int j = 0; j < 8; j++) {
    xv[j] -= mu;
    s2 += xv[j] * xv[j];
  }
#pragma unroll
  for (int off = 1; off < 64; off <<= 1) s2 += __shfl_xor(s2, off);
  float scale = rsqrtf(s2 * (1.0f / 512.0f) + 1e-5f);
  float o[8];
#pragma unroll
  for (int j = 0; j < 8; j++) {
    float wj = w[lane * 8 + j], bj = b[lane * 8 + j];
    o[j] = xv[j] * scale * wj + bj;
  }
  uint4 pk = {(unsigned)f2b(o[0]) | ((unsigned)f2b(o[1]) << 16),
              (unsigned)f2b(o[2]) | ((unsigned)f2b(o[3]) << 16),
              (unsigned)f2b(o[4]) | ((unsigned)f2b(o[5]) << 16),
              (unsigned)f2b(o[6]) | ((unsigned)f2b(o[7]) << 16)};
  *(uint4*)(y + base) = pk;
}

// ---------- finish split-K gemm2 of stack1: h += fb + p0 + p1, also emit bf16 ----------
__global__ __launch_bounds__(256) void finish2(
    const float* __restrict__ p0, const float* __restrict__ p1,
    const float* __restrict__ fb, float* __restrict__ h, bf16* __restrict__ hbf) {
  int i = blockIdx.x * 256 + threadIdx.x;  // 8 elems each; grid covers 2M elems
  size_t base = (size_t)i * 8;
  int col = (int)(base & 511);
  float x[8];
#pragma unroll
  for (int j = 0; j < 8; j += 4) {
    float4 a = *(const float4*)(h + base + j);
    float4 q = *(const float4*)(p0 + base + j);
    float4 r = *(const float4*)(p1 + base + j);
    float4 f = *(const float4*)(fb + col + j);
    x[j] = a.x + q.x + r.x + f.x; x[j + 1] = a.y + q.y + r.y + f.y;
    x[j + 2] = a.z + q.z + r.z + f.z; x[j + 3] = a.w + q.w + r.w + f.w;
    *(float4*)(h + base + j) = make_float4(x[j], x[j + 1], x[j + 2], x[j + 3]);
  }
  uint4 pk = {(unsigned)f2b(x[0]) | ((unsigned)f2b(x[1]) << 16),
              (unsigned)f2b(x[2]) | ((unsigned)f2b(x[3]) << 16),
              (unsigned)f2b(x[4]) | ((unsigned)f2b(x[5]) << 16),
              (unsigned)f2b(x[6]) | ((unsigned)f2b(x[7]) << 16)};
  *(uint4*)(hbf + base) = pk;
}

// ---------- GEMM 128xBN tile, 2-phase dbuf (for N=512 split-K cases) ----------
// EPI 0: out_bf16 = gelu(acc + bias)
// EPI 3: out_f32  = acc
// EPI 4: out_f32[z*M*N + idx] = acc   (split-K partial)
template <int EPI, int BN, bool MSWZ>
__global__ __launch_bounds__(256) void gemm_bt(
    const bf16* __restrict__ A, const bf16* __restrict__ Bt,
    const float* __restrict__ bias, float* __restrict__ outF,
    bf16* __restrict__ outB, int M, int N, int Klen, int lda, int ldb) {
  constexpr int ASZ = 128 * 32;
  constexpr int BSZ = BN * 32;
  constexpr int TILE = ASZ + BSZ;
  __shared__ bf16 lds[2 * TILE];
  const int tid = threadIdx.x;
  const int wave = tid >> 6;
  const int lane = tid & 63;
  constexpr int NF = BN / 32;
  const int wm = (wave >> 1) * 64;
  const int wn = (wave & 1) * (BN / 2);

  int bm, bn;
  if constexpr (MSWZ) {
    const int per = gridDim.x >> 3;
    const int wg = (blockIdx.x & 7) * per + (blockIdx.x >> 3);
    const int nM = M >> 7;
    bm = wg & (nM - 1);
    bn = wg / nM;
  } else {
    bn = blockIdx.x;
    bm = blockIdx.y;
  }
  const int rowA0 = bm * 128;
  const int rowB0 = bn * BN;
  const int k0 = blockIdx.z * Klen;

  const bf16* srcA[2];
#pragma unroll
  for (int r = 0; r < 2; r++) {
    int c = (r * 4 + wave) * 64 + lane;
    srcA[r] = A + (size_t)(rowA0 + (c >> 2)) * lda + k0 + (c & 3) * 8;
  }
  const bf16* srcB[BN / 64];
#pragma unroll
  for (int r = 0; r < BN / 64; r++) {
    int c = (r * 4 + wave) * 64 + lane;
    srcB[r] = Bt + (size_t)(rowB0 + (c >> 2)) * ldb + k0 + (c & 3) * 8;
  }

  f32x4 acc[4][NF];
#pragma unroll
  for (int i = 0; i < 4; i++)
#pragma unroll
    for (int j = 0; j < NF; j++) acc[i][j] = (f32x4){0.f, 0.f, 0.f, 0.f};

  const int fr = lane & 15;
  const int ko = (lane >> 4) * 8;

  auto STAGE = [&](int buf) {
    bf16* dst = lds + buf * TILE;
#pragma unroll
    for (int r = 0; r < 2; r++) {
      load16_lds(srcA[r], dst + (r * 4 + wave) * 512);
      srcA[r] += 32;
    }
#pragma unroll
    for (int r = 0; r < BN / 64; r++) {
      load16_lds(srcB[r], dst + ASZ + (r * 4 + wave) * 512);
      srcB[r] += 32;
    }
  };

  STAGE(0);
  __syncthreads();
  const int nIter = Klen >> 5;
  for (int it = 0; it < nIter; ++it) {
    const int cur = it & 1;
    if (it + 1 < nIter) STAGE(cur ^ 1);
    const bf16* lA = lds + cur * TILE;
    const bf16* lB = lA + ASZ;
    bf16x8 af[4], bfr[NF];
#pragma unroll
    for (int f = 0; f < 4; f++)
      af[f] = *(const bf16x8*)(lA + (wm + f * 16 + fr) * 32 + ko);
#pragma unroll
    for (int f = 0; f < NF; f++)
      bfr[f] = *(const bf16x8*)(lB + (wn + f * 16 + fr) * 32 + ko);
#pragma unroll
    for (int i = 0; i < 4; i++)
#pragma unroll
      for (int j = 0; j < NF; j++)
        acc[i][j] = __builtin_amdgcn_mfma_f32_16x16x32_bf16(af[i], bfr[j], acc[i][j], 0, 0, 0);
    __syncthreads();
  }

  if constexpr (EPI == 4) outF += (size_t)blockIdx.z * M * N;
  const int orow = (lane >> 4) * 4;
  const int ocol = lane & 15;
#pragma unroll
  for (int i = 0; i < 4; i++) {
#pragma unroll
    for (int j = 0; j < NF; j++) {
      int row0 = rowA0 + wm + i * 16 + orow;
      int col = rowB0 + wn + j * 16 + ocol;
#pragma unroll
      for (int q = 0; q < 4; q++) {
        float v = acc[i][j][q];
        size_t idx = (size_t)(row0 + q) * N + col;
        if constexpr (EPI == 0) {
          outB[idx] = (bf16)gelu_tanh(v + bias[col]);
        } else {
          outF[idx] = v;
        }
      }
    }
  }
}

// ---------- GEMM 256x128 tile, 512 threads, 2-phase dbuf (gemm1 + logits) ----------
// 8 waves as 4M x 2N; each wave: 64x64 sub-tile (16 MFMA + 8 ds_read_b128 / K-step).
// Staging per K-step: A 256x32 (2 rounds) + B 128x32 (1 round) = 3 x 16B/thread.
// EPI 0: out_bf16 = gelu(acc + bias);  EPI 3: out_f32 = acc (logits, XCD swizzle)
template <int EPI, bool MSWZ>
__global__ __launch_bounds__(512) void gemm_bt256(
    const bf16* __restrict__ A, const bf16* __restrict__ Bt,
    const float* __restrict__ bias, float* __restrict__ outF,
    bf16* __restrict__ outB, int M, int N, int lda, int ldb) {
  constexpr int ASZ = 256 * 32;
  constexpr int BSZ = 128 * 32;
  constexpr int TILE = ASZ + BSZ;  // 12288 elems = 24 KB
  __shared__ bf16 lds[2 * TILE];   // 48 KB
  const int tid = threadIdx.x;
  const int wave = tid >> 6;
  const int lane = tid & 63;
  const int wm = (wave >> 1) * 64;  // 0,64,128,192
  const int wn = (wave & 1) * 64;   // 0,64

  int bm, bn;
  if constexpr (MSWZ) {
    const int per = gridDim.x >> 3;
    const int wg = (blockIdx.x & 7) * per + (blockIdx.x >> 3);
    const int nM = M >> 8;  // 16 (power of 2)
    bm = wg & (nM - 1);
    bn = wg / nM;
  } else {
    bn = blockIdx.x;
    bm = blockIdx.y;
  }
  const int rowA0 = bm * 256;
  const int rowB0 = bn * 128;

  const bf16* srcA[2];
#pragma unroll
  for (int r = 0; r < 2; r++) {
    int c = r * 512 + tid;  // 0..1023 over A tile chunks
    srcA[r] = A + (size_t)(rowA0 + (c >> 2)) * lda + (c & 3) * 8;
  }
  int cB = tid;  // 0..511 over B tile chunks
  const bf16* srcB = Bt + (size_t)(rowB0 + (cB >> 2)) * ldb + (cB & 3) * 8;

  f32x4 acc[4][4];
#pragma unroll
  for (int i = 0; i < 4; i++)
#pragma unroll
    for (int j = 0; j < 4; j++) acc[i][j] = (f32x4){0.f, 0.f, 0.f, 0.f};

  const int fr = lane & 15;
  const int ko = (lane >> 4) * 8;

  auto STAGE = [&](int buf) {
    bf16* dst = lds + buf * TILE;
#pragma unroll
    for (int r = 0; r < 2; r++) {
      load16_lds(srcA[r], dst + (r * 512 + tid) * 8);
      srcA[r] += 32;
    }
    load16_lds(srcB, dst + ASZ + tid * 8);
    srcB += 32;
  };

  STAGE(0);
  __syncthreads();
  const int nIter = 512 >> 5;  // K = Hd = 512 always
  for (int it = 0; it < nIter; ++it) {
    const int cur = it & 1;
    if (it + 1 < nIter) STAGE(cur ^ 1);
    const bf16* lA = lds + cur * TILE;
    const bf16* lB = lA + ASZ;
    bf16x8 af[4], bfr[4];
#pragma unroll
    for (int f = 0; f < 4; f++)
      af[f] = *(const bf16x8*)(lA + (wm + f * 16 + fr) * 32 + ko);
#pragma unroll
    for (int f = 0; f < 4; f++)
      bfr[f] = *(const bf16x8*)(lB + (wn + f * 16 + fr) * 32 + ko);
#pragma unroll
    for (int i = 0; i < 4; i++)
#pragma unroll
      for (int j = 0; j < 4; j++)
        acc[i][j] = __builtin_amdgcn_mfma_f32_16x16x32_bf16(af[i], bfr[j], acc[i][j], 0, 0, 0);
    __syncthreads();
  }

  const int orow = (lane >> 4) * 4;
  const int ocol = lane & 15;
#pragma unroll
  for (int i = 0; i < 4; i++) {
#pragma unroll
    for (int j = 0; j < 4; j++) {
      int row0 = rowA0 + wm + i * 16 + orow;
      int col = rowB0 + wn + j * 16 + ocol;
#pragma unroll
      for (int q = 0; q < 4; q++) {
        float v = acc[i][j][q];
        size_t idx = (size_t)(row0 + q) * N + col;
        if constexpr (EPI == 0) {
          outB[idx] = (bf16)gelu_tanh(v + bias[col]);
        } else {
          outF[idx] = v;
        }
      }
    }
  }
}

// ---------- final hidden: h[:, -1, :] -> out ----------
__global__ void tail_copy(const float* __restrict__ h, float* __restrict__ out) {
  int t = blockIdx.x * 256 + threadIdx.x;  // 0..2047
  int b = t >> 9, k = t & 511;
  out[t] = h[((size_t)(b * 1024 + 1023)) * Hd + k];
}

// ---------- launch ----------
extern "C" void kernel_launch(void* const* d_in, const int* in_sizes, int n_in,
                              void* d_out, int out_size, void* d_ws, size_t ws_size,
                              hipStream_t stream) {
  const int* ids = (const int*)d_in[0];
  const float* emb = (const float*)d_in[1];
  const float* hp_w = (const float*)d_in[2];
  const float* hp_b = (const float*)d_in[3];
  const float* ln_w = (const float*)d_in[4];
  const float* ln_b = (const float*)d_in[5];
  const float* W1 = (const float*)d_in[6];
  const float* b1 = (const float*)d_in[7];
  const float* W2 = (const float*)d_in[8];
  const float* b2 = (const float*)d_in[9];
  const float* lnf_w = (const float*)d_in[10];
  const float* lnf_b = (const float*)d_in[11];
  const float* eow = (const float*)d_in[12];
  float* out = (float*)d_out;

  char* ws = (char*)d_ws;
  float* h = (float*)(ws);                          // 8 MB
  bf16* ybf = (bf16*)(ws + (8u << 20));             // 4 MB (LN out / hbf for hp)
  bf16* abf = (bf16*)(ws + (12u << 20));            // 16 MB (gelu activations)
  bf16* W1t = (bf16*)(ws + (28u << 20));            // 12 MB
  bf16* W2t = (bf16*)(ws + (40u << 20));            // 12 MB
  bf16* hpwB = (bf16*)(ws + (52u << 20));           // 0.5 MB
  bf16* eowB = (bf16*)(ws + (53u << 20));           // 51.5 MB

  // split-K partials live in d_out's logits region (overwritten by logits GEMM later)
  float* p0 = out;                    // 2M floats
  float* p1 = out + (size_t)Md * Hd;  // next 2M floats

  // weight prep (bf16 cast; W1/W2 transposed to (N,K))
  cast8<<<dim3(Vd * Hd / 8 / 256), dim3(256), 0, stream>>>(eow, eowB, Vd * Hd / 8);
  cast8<<<dim3(Hd * Hd / 8 / 256), dim3(256), 0, stream>>>(hp_w, hpwB, Hd * Hd / 8);
  transpose_cast<<<dim3(Fd / 32, Hd / 32, Ld), dim3(32, 8), 0, stream>>>(W1, W1t, Hd, Fd);
  transpose_cast<<<dim3(Hd / 32, Fd / 32, Ld), dim3(32, 8), 0, stream>>>(W2, W2t, Fd, Hd);

  gather_embed<<<dim3(Md), dim3(128), 0, stream>>>(ids, emb, h);

  // one MLP layer: ln (with optional fused finish) -> gemm1(256-tile) -> split-K gemm2
  auto layer = [&](int l, int mode, const float* fb, const float* lw, const float* lb) {
    if (mode == 0)
      ln_rows<0><<<dim3(Md / 4), dim3(256), 0, stream>>>(h, p0, p1, fb, lw, lb, h, ybf);
    else if (mode == 1)
      ln_rows<1><<<dim3(Md / 4), dim3(256), 0, stream>>>(h, p0, p1, fb, lw, lb, h, ybf);
    else
      ln_rows<2><<<dim3(Md / 4), dim3(256), 0, stream>>>(h, p0, p1, fb, lw, lb, h, ybf);
    gemm_bt256<0, false><<<dim3(Fd / 128, Md / 256), dim3(512), 0, stream>>>(
        ybf, W1t + (size_t)l * Fd * Hd, b1 + (size_t)l * Fd, (float*)nullptr, abf,
        Md, Fd, Hd, Hd);
    gemm_bt<4, 64, false><<<dim3(Hd / 64, Md / 128, 2), dim3(256), 0, stream>>>(
        abf, W2t + (size_t)l * Hd * Fd, (const float*)nullptr, p0, (bf16*)nullptr,
        Md, Hd, Fd / 2, Fd, Fd);
  };

  // ---- stack 1 ----
  layer(0, 0, nullptr, ln_w, ln_b);
  for (int l = 1; l < Ld; l++)
    layer(l, 1, b2 + (size_t)(l - 1) * Hd, ln_w + (size_t)l * Hd, ln_b + (size_t)l * Hd);
  // finish layer 5 + emit bf16 for hp
  finish2<<<dim3(Md * Hd / 8 / 256), dim3(256), 0, stream>>>(
      p0, p1, b2 + (size_t)(Ld - 1) * Hd, h, ybf);

  // ---- hp projection: h @ hp_w^T + hp_b (split-K=2, finish fused into next LN) ----
  gemm_bt<4, 64, false><<<dim3(Hd / 64, Md / 128, 2), dim3(256), 0, stream>>>(
      ybf, hpwB, (const float*)nullptr, p0, (bf16*)nullptr, Md, Hd, Hd / 2, Hd, Hd);

  // ---- stack 2 ----
  layer(0, 2, hp_b, ln_w, ln_b);
  for (int l = 1; l < Ld; l++)
    layer(l, 1, b2 + (size_t)(l - 1) * Hd, ln_w + (size_t)l * Hd, ln_b + (size_t)l * Hd);

  // ---- final LN (fused finish of last gemm2) + logits (256-tile, XCD swizzle) ----
  ln_rows<1><<<dim3(Md / 4), dim3(256), 0, stream>>>(
      h, p0, p1, b2 + (size_t)(Ld - 1) * Hd, lnf_w, lnf_b, h, ybf);
  gemm_bt256<3, true><<<dim3((Vd / 128) * (Md / 256)), dim3(512), 0, stream>>>(
      ybf, eowB, (const float*)nullptr, out, (bf16*)nullptr, Md, Vd, Hd, Hd);

  // final hidden
  tail_copy<<<dim3(8), dim3(256), 0, stream>>>(h, out + (size_t)Md * Vd);
}

// Round 6
// 1077.756 us; speedup vs baseline: 1.2923x; 1.0131x over previous
//
#include <hip/hip_runtime.h>
#include <hip/hip_bf16.h>
#include <cstdint>

using bf16 = __hip_bfloat16;
typedef __bf16 bf16x8 __attribute__((ext_vector_type(8)));
typedef float f32x4 __attribute__((ext_vector_type(4)));

constexpr int Hd = 512;
constexpr int Ld = 6;
constexpr int Fd = 2048;
constexpr int Vd = 50304;
constexpr int Md = 4096;  // B*S = 4*1024

// ---------- helpers ----------
__device__ __forceinline__ unsigned short f2b(float x) {
  return __builtin_bit_cast(unsigned short, __float2bfloat16(x));
}

__device__ __forceinline__ float gelu_tanh(float x) {
  const float c = 0.7978845608028654f;  // sqrt(2/pi)
  float x3 = x * x * x;
  return 0.5f * x * (1.0f + tanhf(c * (x + 0.044715f * x3)));
}

__device__ __forceinline__ void load16_lds(const bf16* g, bf16* l) {
  __builtin_amdgcn_global_load_lds(
      (const __attribute__((address_space(1))) void*)g,
      (__attribute__((address_space(3))) void*)l, 16, 0, 0);
}

// ---------- cast fp32 -> bf16, 8 elems/thread ----------
__global__ __launch_bounds__(256) void cast8(const float* __restrict__ in,
                                             bf16* __restrict__ out, int n8) {
  int i = blockIdx.x * 256 + threadIdx.x;
  if (i >= n8) return;
  const float4* p = (const float4*)in;
  float4 a = p[2 * i], b = p[2 * i + 1];
  uint4 o = {(unsigned)f2b(a.x) | ((unsigned)f2b(a.y) << 16),
             (unsigned)f2b(a.z) | ((unsigned)f2b(a.w) << 16),
             (unsigned)f2b(b.x) | ((unsigned)f2b(b.y) << 16),
             (unsigned)f2b(b.z) | ((unsigned)f2b(b.w) << 16)};
  ((uint4*)out)[i] = o;
}

// ---------- transpose+cast: in (R,C) f32 -> out (C,R) bf16, batched over z ----------
__global__ void transpose_cast(const float* __restrict__ in, bf16* __restrict__ out,
                               int R, int C) {
  __shared__ float tile[32][33];
  int l = blockIdx.z;
  in += (size_t)l * R * C;
  out += (size_t)l * R * C;
  int c0 = blockIdx.x * 32, r0 = blockIdx.y * 32;
#pragma unroll
  for (int i = 0; i < 4; i++) {
    int r = r0 + threadIdx.y + i * 8;
    tile[threadIdx.y + i * 8][threadIdx.x] = in[(size_t)r * C + c0 + threadIdx.x];
  }
  __syncthreads();
#pragma unroll
  for (int i = 0; i < 4; i++) {
    int c = c0 + threadIdx.y + i * 8;
    out[(size_t)c * R + r0 + threadIdx.x] = (bf16)tile[threadIdx.x][threadIdx.y + i * 8];
  }
}

// ---------- embedding gather ----------
__global__ void gather_embed(const int* __restrict__ ids, const float* __restrict__ emb,
                             float* __restrict__ h) {
  int row = blockIdx.x;
  int id = ids[row];
  const float4* src = (const float4*)(emb + (size_t)id * Hd);
  float4* dst = (float4*)(h + (size_t)row * Hd);
  dst[threadIdx.x] = src[threadIdx.x];
}

// ---------- layernorm, one wave per row, with fused split-K reduce ----------
// MODE 0: x = h[row]                         (plain LN)
// MODE 1: x = h + fb[col] + p0 + p1; h = x   (finish gemm2 split-K + residual)
// MODE 2: x = p0 + p1 + fb[col];    h = x    (finish hp split-K, overwrite)
template <int MODE>
__global__ __launch_bounds__(256) void ln_rows(
    const float* __restrict__ h, const float* __restrict__ p0,
    const float* __restrict__ p1, const float* __restrict__ fb,
    const float* __restrict__ w, const float* __restrict__ b,
    float* __restrict__ hout, bf16* __restrict__ y) {
  int row = blockIdx.x * 4 + (threadIdx.x >> 6);
  int lane = threadIdx.x & 63;
  size_t base = (size_t)row * Hd + lane * 8;
  float xv[8];
  if constexpr (MODE == 0) {
    *(float4*)&xv[0] = *(const float4*)(h + base);
    *(float4*)&xv[4] = *(const float4*)(h + base + 4);
  } else {
    float4 q0 = *(const float4*)(p0 + base), q1 = *(const float4*)(p0 + base + 4);
    float4 r0 = *(const float4*)(p1 + base), r1 = *(const float4*)(p1 + base + 4);
    float4 f0 = *(const float4*)(fb + lane * 8), f1 = *(const float4*)(fb + lane * 8 + 4);
    xv[0] = q0.x + r0.x + f0.x; xv[1] = q0.y + r0.y + f0.y;
    xv[2] = q0.z + r0.z + f0.z; xv[3] = q0.w + r0.w + f0.w;
    xv[4] = q1.x + r1.x + f1.x; xv[5] = q1.y + r1.y + f1.y;
    xv[6] = q1.z + r1.z + f1.z; xv[7] = q1.w + r1.w + f1.w;
    if constexpr (MODE == 1) {
      float4 a0 = *(const float4*)(h + base), a1 = *(const float4*)(h + base + 4);
      xv[0] += a0.x; xv[1] += a0.y; xv[2] += a0.z; xv[3] += a0.w;
      xv[4] += a1.x; xv[5] += a1.y; xv[6] += a1.z; xv[7] += a1.w;
    }
    *(float4*)(hout + base) = make_float4(xv[0], xv[1], xv[2], xv[3]);
    *(float4*)(hout + base + 4) = make_float4(xv[4], xv[5], xv[6], xv[7]);
  }
  float s = 0.f;
#pragma unroll
  for (int j = 0; j < 8; j++) s += xv[j];
#pragma unroll
  for (int off = 1; off < 64; off <<= 1) s += __shfl_xor(s, off);
  float mu = s * (1.0f / 512.0f);
  float s2 = 0.f;
#pragma unroll
  for (int j = 0; j < 8; j++) {
    xv[j] -= mu;
    s2 += xv[j] * xv[j];
  }
#pragma unroll
  for (int off = 1; off < 64; off <<= 1) s2 += __shfl_xor(s2, off);
  float scale = rsqrtf(s2 * (1.0f / 512.0f) + 1e-5f);
  float o[8];
#pragma unroll
  for (int j = 0; j < 8; j++) {
    float wj = w[lane * 8 + j], bj = b[lane * 8 + j];
    o[j] = xv[j] * scale * wj + bj;
  }
  uint4 pk = {(unsigned)f2b(o[0]) | ((unsigned)f2b(o[1]) << 16),
              (unsigned)f2b(o[2]) | ((unsigned)f2b(o[3]) << 16),
              (unsigned)f2b(o[4]) | ((unsigned)f2b(o[5]) << 16),
              (unsigned)f2b(o[6]) | ((unsigned)f2b(o[7]) << 16)};
  *(uint4*)(y + base) = pk;
}

// ---------- finish split-K gemm2 of stack1: h += fb + p0 + p1, also emit bf16 ----------
__global__ __launch_bounds__(256) void finish2(
    const float* __restrict__ p0, const float* __restrict__ p1,
    const float* __restrict__ fb, float* __restrict__ h, bf16* __restrict__ hbf) {
  int i = blockIdx.x * 256 + threadIdx.x;  // 8 elems each; grid covers 2M elems
  size_t base = (size_t)i * 8;
  int col = (int)(base & 511);
  float x[8];
#pragma unroll
  for (int j = 0; j < 8; j += 4) {
    float4 a = *(const float4*)(h + base + j);
    float4 q = *(const float4*)(p0 + base + j);
    float4 r = *(const float4*)(p1 + base + j);
    float4 f = *(const float4*)(fb + col + j);
    x[j] = a.x + q.x + r.x + f.x; x[j + 1] = a.y + q.y + r.y + f.y;
    x[j + 2] = a.z + q.z + r.z + f.z; x[j + 3] = a.w + q.w + r.w + f.w;
    *(float4*)(h + base + j) = make_float4(x[j], x[j + 1], x[j + 2], x[j + 3]);
  }
  uint4 pk = {(unsigned)f2b(x[0]) | ((unsigned)f2b(x[1]) << 16),
              (unsigned)f2b(x[2]) | ((unsigned)f2b(x[3]) << 16),
              (unsigned)f2b(x[4]) | ((unsigned)f2b(x[5]) << 16),
              (unsigned)f2b(x[6]) | ((unsigned)f2b(x[7]) << 16)};
  *(uint4*)(hbf + base) = pk;
}

// ---------- GEMM 128xBN tile, 256 thr, 3-slot pipeline, counted vmcnt ----------
// EPI 0: out_bf16 = gelu(acc + bias)
// EPI 3: out_f32  = acc
// EPI 4: out_f32[z*M*N + idx] = acc   (split-K partial)
// Loads/thread/STAGE: 2 (A) + BN/64 (B).
template <int EPI, int BN, bool MSWZ>
__global__ __launch_bounds__(256) void gemm_bt(
    const bf16* __restrict__ A, const bf16* __restrict__ Bt,
    const float* __restrict__ bias, float* __restrict__ outF,
    bf16* __restrict__ outB, int M, int N, int Klen, int lda, int ldb) {
  constexpr int ASZ = 128 * 32;
  constexpr int BSZ = BN * 32;
  constexpr int TILE = ASZ + BSZ;
  __shared__ bf16 lds[3 * TILE];
  const int tid = threadIdx.x;
  const int wave = tid >> 6;
  const int lane = tid & 63;
  constexpr int NF = BN / 32;
  const int wm = (wave >> 1) * 64;
  const int wn = (wave & 1) * (BN / 2);

  int bm, bn;
  if constexpr (MSWZ) {
    const int per = gridDim.x >> 3;
    const int wg = (blockIdx.x & 7) * per + (blockIdx.x >> 3);
    const int nM = M >> 7;
    bm = wg & (nM - 1);
    bn = wg / nM;
  } else {
    bn = blockIdx.x;
    bm = blockIdx.y;
  }
  const int rowA0 = bm * 128;
  const int rowB0 = bn * BN;
  const int k0 = blockIdx.z * Klen;

  const bf16* srcA[2];
#pragma unroll
  for (int r = 0; r < 2; r++) {
    int c = (r * 4 + wave) * 64 + lane;
    srcA[r] = A + (size_t)(rowA0 + (c >> 2)) * lda + k0 + (c & 3) * 8;
  }
  const bf16* srcB[BN / 64];
#pragma unroll
  for (int r = 0; r < BN / 64; r++) {
    int c = (r * 4 + wave) * 64 + lane;
    srcB[r] = Bt + (size_t)(rowB0 + (c >> 2)) * ldb + k0 + (c & 3) * 8;
  }

  f32x4 acc[4][NF];
#pragma unroll
  for (int i = 0; i < 4; i++)
#pragma unroll
    for (int j = 0; j < NF; j++) acc[i][j] = (f32x4){0.f, 0.f, 0.f, 0.f};

  const int fr = lane & 15;
  const int ko = (lane >> 4) * 8;

  auto STAGE = [&](int slot) {
    bf16* dst = lds + slot * TILE;
#pragma unroll
    for (int r = 0; r < 2; r++) {
      load16_lds(srcA[r], dst + (r * 4 + wave) * 512);
      srcA[r] += 32;
    }
#pragma unroll
    for (int r = 0; r < BN / 64; r++) {
      load16_lds(srcB[r], dst + ASZ + (r * 4 + wave) * 512);
      srcB[r] += 32;
    }
  };

  STAGE(0);
  STAGE(1);
  const int nIter = Klen >> 5;
  int cur = 0, stg = 2;
  for (int it = 0; it < nIter; ++it) {
    // per-wave: leave next tile's loads in flight; all waves do this BEFORE the
    // barrier, so after the barrier tile-cur is complete chip-wide.
    if (it < nIter - 1) {
      if constexpr (BN == 64)
        asm volatile("s_waitcnt vmcnt(3)" ::: "memory");
      else
        asm volatile("s_waitcnt vmcnt(4)" ::: "memory");
    } else {
      asm volatile("s_waitcnt vmcnt(0)" ::: "memory");
    }
    __builtin_amdgcn_s_barrier();
    __builtin_amdgcn_sched_barrier(0);  // pin: no ds_read hoisted above barrier
    if (it + 2 < nIter) STAGE(stg);
    const bf16* lA = lds + cur * TILE;
    const bf16* lB = lA + ASZ;
    bf16x8 af[4], bfr[NF];
#pragma unroll
    for (int f = 0; f < 4; f++)
      af[f] = *(const bf16x8*)(lA + (wm + f * 16 + fr) * 32 + ko);
#pragma unroll
    for (int f = 0; f < NF; f++)
      bfr[f] = *(const bf16x8*)(lB + (wn + f * 16 + fr) * 32 + ko);
#pragma unroll
    for (int i = 0; i < 4; i++)
#pragma unroll
      for (int j = 0; j < NF; j++)
        acc[i][j] = __builtin_amdgcn_mfma_f32_16x16x32_bf16(af[i], bfr[j], acc[i][j], 0, 0, 0);
    cur = (cur == 2) ? 0 : cur + 1;
    stg = (stg == 2) ? 0 : stg + 1;
  }

  if constexpr (EPI == 4) outF += (size_t)blockIdx.z * M * N;
  const int orow = (lane >> 4) * 4;
  const int ocol = lane & 15;
#pragma unroll
  for (int i = 0; i < 4; i++) {
#pragma unroll
    for (int j = 0; j < NF; j++) {
      int row0 = rowA0 + wm + i * 16 + orow;
      int col = rowB0 + wn + j * 16 + ocol;
#pragma unroll
      for (int q = 0; q < 4; q++) {
        float v = acc[i][j][q];
        size_t idx = (size_t)(row0 + q) * N + col;
        if constexpr (EPI == 0) {
          outB[idx] = (bf16)gelu_tanh(v + bias[col]);
        } else {
          outF[idx] = v;
        }
      }
    }
  }
}

// ---------- GEMM 256x128 tile, 512 thr, 3-slot pipeline, counted vmcnt ----------
// 8 waves as 4M x 2N; loads/thread/STAGE = 2 (A) + 1 (B) = 3.
// EPI 0: out_bf16 = gelu(acc + bias);  EPI 3: out_f32 = acc (logits, XCD swizzle)
template <int EPI, bool MSWZ>
__global__ __launch_bounds__(512) void gemm_bt256(
    const bf16* __restrict__ A, const bf16* __restrict__ Bt,
    const float* __restrict__ bias, float* __restrict__ outF,
    bf16* __restrict__ outB, int M, int N, int lda, int ldb) {
  constexpr int ASZ = 256 * 32;
  constexpr int BSZ = 128 * 32;
  constexpr int TILE = ASZ + BSZ;  // 12288 elems = 24 KB
  __shared__ bf16 lds[3 * TILE];   // 72 KB
  const int tid = threadIdx.x;
  const int wave = tid >> 6;
  const int lane = tid & 63;
  const int wm = (wave >> 1) * 64;  // 0,64,128,192
  const int wn = (wave & 1) * 64;   // 0,64

  int bm, bn;
  if constexpr (MSWZ) {
    const int per = gridDim.x >> 3;
    const int wg = (blockIdx.x & 7) * per + (blockIdx.x >> 3);
    const int nM = M >> 8;  // 16 (power of 2)
    bm = wg & (nM - 1);
    bn = wg / nM;
  } else {
    bn = blockIdx.x;
    bm = blockIdx.y;
  }
  const int rowA0 = bm * 256;
  const int rowB0 = bn * 128;

  const bf16* srcA[2];
#pragma unroll
  for (int r = 0; r < 2; r++) {
    int c = r * 512 + tid;
    srcA[r] = A + (size_t)(rowA0 + (c >> 2)) * lda + (c & 3) * 8;
  }
  int cB = tid;
  const bf16* srcB = Bt + (size_t)(rowB0 + (cB >> 2)) * ldb + (cB & 3) * 8;

  f32x4 acc[4][4];
#pragma unroll
  for (int i = 0; i < 4; i++)
#pragma unroll
    for (int j = 0; j < 4; j++) acc[i][j] = (f32x4){0.f, 0.f, 0.f, 0.f};

  const int fr = lane & 15;
  const int ko = (lane >> 4) * 8;

  auto STAGE = [&](int slot) {
    bf16* dst = lds + slot * TILE;
#pragma unroll
    for (int r = 0; r < 2; r++) {
      load16_lds(srcA[r], dst + (r * 512 + tid) * 8);
      srcA[r] += 32;
    }
    load16_lds(srcB, dst + ASZ + tid * 8);
    srcB += 32;
  };

  STAGE(0);
  STAGE(1);
  const int nIter = 512 >> 5;  // K = Hd = 512 always
  int cur = 0, stg = 2;
  for (int it = 0; it < nIter; ++it) {
    if (it < nIter - 1)
      asm volatile("s_waitcnt vmcnt(3)" ::: "memory");
    else
      asm volatile("s_waitcnt vmcnt(0)" ::: "memory");
    __builtin_amdgcn_s_barrier();
    __builtin_amdgcn_sched_barrier(0);
    if (it + 2 < nIter) STAGE(stg);
    const bf16* lA = lds + cur * TILE;
    const bf16* lB = lA + ASZ;
    bf16x8 af[4], bfr[4];
#pragma unroll
    for (int f = 0; f < 4; f++)
      af[f] = *(const bf16x8*)(lA + (wm + f * 16 + fr) * 32 + ko);
#pragma unroll
    for (int f = 0; f < 4; f++)
      bfr[f] = *(const bf16x8*)(lB + (wn + f * 16 + fr) * 32 + ko);
#pragma unroll
    for (int i = 0; i < 4; i++)
#pragma unroll
      for (int j = 0; j < 4; j++)
        acc[i][j] = __builtin_amdgcn_mfma_f32_16x16x32_bf16(af[i], bfr[j], acc[i][j], 0, 0, 0);
    cur = (cur == 2) ? 0 : cur + 1;
    stg = (stg == 2) ? 0 : stg + 1;
  }

  const int orow = (lane >> 4) * 4;
  const int ocol = lane & 15;
#pragma unroll
  for (int i = 0; i < 4; i++) {
#pragma unroll
    for (int j = 0; j < 4; j++) {
      int row0 = rowA0 + wm + i * 16 + orow;
      int col = rowB0 + wn + j * 16 + ocol;
#pragma unroll
      for (int q = 0; q < 4; q++) {
        float v = acc[i][j][q];
        size_t idx = (size_t)(row0 + q) * N + col;
        if constexpr (EPI == 0) {
          outB[idx] = (bf16)gelu_tanh(v + bias[col]);
        } else {
          outF[idx] = v;
        }
      }
    }
  }
}

// ---------- final hidden: h[:, -1, :] -> out ----------
__global__ void tail_copy(const float* __restrict__ h, float* __restrict__ out) {
  int t = blockIdx.x * 256 + threadIdx.x;  // 0..2047
  int b = t >> 9, k = t & 511;
  out[t] = h[((size_t)(b * 1024 + 1023)) * Hd + k];
}

// ---------- launch ----------
extern "C" void kernel_launch(void* const* d_in, const int* in_sizes, int n_in,
                              void* d_out, int out_size, void* d_ws, size_t ws_size,
                              hipStream_t stream) {
  const int* ids = (const int*)d_in[0];
  const float* emb = (const float*)d_in[1];
  const float* hp_w = (const float*)d_in[2];
  const float* hp_b = (const float*)d_in[3];
  const float* ln_w = (const float*)d_in[4];
  const float* ln_b = (const float*)d_in[5];
  const float* W1 = (const float*)d_in[6];
  const float* b1 = (const float*)d_in[7];
  const float* W2 = (const float*)d_in[8];
  const float* b2 = (const float*)d_in[9];
  const float* lnf_w = (const float*)d_in[10];
  const float* lnf_b = (const float*)d_in[11];
  const float* eow = (const float*)d_in[12];
  float* out = (float*)d_out;

  char* ws = (char*)d_ws;
  float* h = (float*)(ws);                          // 8 MB
  bf16* ybf = (bf16*)(ws + (8u << 20));             // 4 MB (LN out / hbf for hp)
  bf16* abf = (bf16*)(ws + (12u << 20));            // 16 MB (gelu activations)
  bf16* W1t = (bf16*)(ws + (28u << 20));            // 12 MB
  bf16* W2t = (bf16*)(ws + (40u << 20));            // 12 MB
  bf16* hpwB = (bf16*)(ws + (52u << 20));           // 0.5 MB
  bf16* eowB = (bf16*)(ws + (53u << 20));           // 51.5 MB

  // split-K partials live in d_out's logits region (overwritten by logits GEMM later)
  float* p0 = out;                    // 2M floats
  float* p1 = out + (size_t)Md * Hd;  // next 2M floats

  // weight prep (bf16 cast; W1/W2 transposed to (N,K))
  cast8<<<dim3(Vd * Hd / 8 / 256), dim3(256), 0, stream>>>(eow, eowB, Vd * Hd / 8);
  cast8<<<dim3(Hd * Hd / 8 / 256), dim3(256), 0, stream>>>(hp_w, hpwB, Hd * Hd / 8);
  transpose_cast<<<dim3(Fd / 32, Hd / 32, Ld), dim3(32, 8), 0, stream>>>(W1, W1t, Hd, Fd);
  transpose_cast<<<dim3(Hd / 32, Fd / 32, Ld), dim3(32, 8), 0, stream>>>(W2, W2t, Fd, Hd);

  gather_embed<<<dim3(Md), dim3(128), 0, stream>>>(ids, emb, h);

  // one MLP layer: ln (with optional fused finish) -> gemm1(256-tile) -> split-K gemm2
  auto layer = [&](int l, int mode, const float* fb, const float* lw, const float* lb) {
    if (mode == 0)
      ln_rows<0><<<dim3(Md / 4), dim3(256), 0, stream>>>(h, p0, p1, fb, lw, lb, h, ybf);
    else if (mode == 1)
      ln_rows<1><<<dim3(Md / 4), dim3(256), 0, stream>>>(h, p0, p1, fb, lw, lb, h, ybf);
    else
      ln_rows<2><<<dim3(Md / 4), dim3(256), 0, stream>>>(h, p0, p1, fb, lw, lb, h, ybf);
    gemm_bt256<0, false><<<dim3(Fd / 128, Md / 256), dim3(512), 0, stream>>>(
        ybf, W1t + (size_t)l * Fd * Hd, b1 + (size_t)l * Fd, (float*)nullptr, abf,
        Md, Fd, Hd, Hd);
    gemm_bt<4, 64, false><<<dim3(Hd / 64, Md / 128, 2), dim3(256), 0, stream>>>(
        abf, W2t + (size_t)l * Hd * Fd, (const float*)nullptr, p0, (bf16*)nullptr,
        Md, Hd, Fd / 2, Fd, Fd);
  };

  // ---- stack 1 ----
  layer(0, 0, nullptr, ln_w, ln_b);
  for (int l = 1; l < Ld; l++)
    layer(l, 1, b2 + (size_t)(l - 1) * Hd, ln_w + (size_t)l * Hd, ln_b + (size_t)l * Hd);
  // finish layer 5 + emit bf16 for hp
  finish2<<<dim3(Md * Hd / 8 / 256), dim3(256), 0, stream>>>(
      p0, p1, b2 + (size_t)(Ld - 1) * Hd, h, ybf);

  // ---- hp projection: h @ hp_w^T + hp_b (split-K=2, finish fused into next LN) ----
  gemm_bt<4, 64, false><<<dim3(Hd / 64, Md / 128, 2), dim3(256), 0, stream>>>(
      ybf, hpwB, (const float*)nullptr, p0, (bf16*)nullptr, Md, Hd, Hd / 2, Hd, Hd);

  // ---- stack 2 ----
  layer(0, 2, hp_b, ln_w, ln_b);
  for (int l = 1; l < Ld; l++)
    layer(l, 1, b2 + (size_t)(l - 1) * Hd, ln_w + (size_t)l * Hd, ln_b + (size_t)l * Hd);

  // ---- final LN (fused finish of last gemm2) + logits (256-tile, XCD swizzle) ----
  ln_rows<1><<<dim3(Md / 4), dim3(256), 0, stream>>>(
      h, p0, p1, b2 + (size_t)(Ld - 1) * Hd, lnf_w, lnf_b, h, ybf);
  gemm_bt256<3, true><<<dim3((Vd / 128) * (Md / 256)), dim3(512), 0, stream>>>(
      ybf, eowB, (const float*)nullptr, out, (bf16*)nullptr, Md, Vd, Hd, Hd);

  // final hidden
  tail_copy<<<dim3(8), dim3(256), 0, stream>>>(h, out + (size_t)Md * Vd);
}

// Round 7
// 984.072 us; speedup vs baseline: 1.4153x; 1.0952x over previous
//
#include <hip/hip_runtime.h>
#include <hip/hip_bf16.h>
#include <cstdint>

using bf16 = __hip_bfloat16;
typedef __bf16 bf16x8 __attribute__((ext_vector_type(8)));
typedef float f32x4 __attribute__((ext_vector_type(4)));

constexpr int Hd = 512;
constexpr int Ld = 6;
constexpr int Fd = 2048;
constexpr int Vd = 50304;
constexpr int Vpad = 50432;  // 197*256
constexpr int Md = 4096;     // B*S = 4*1024

// ---------- helpers ----------
__device__ __forceinline__ unsigned short f2b(float x) {
  return __builtin_bit_cast(unsigned short, __float2bfloat16(x));
}

__device__ __forceinline__ float gelu_tanh(float x) {
  const float c = 0.7978845608028654f;  // sqrt(2/pi)
  float x3 = x * x * x;
  return 0.5f * x * (1.0f + tanhf(c * (x + 0.044715f * x3)));
}

__device__ __forceinline__ void load16_lds(const bf16* g, bf16* l) {
  __builtin_amdgcn_global_load_lds(
      (const __attribute__((address_space(1))) void*)g,
      (__attribute__((address_space(3))) void*)l, 16, 0, 0);
}

// ---------- cast fp32 -> bf16, 8 elems/thread ----------
__global__ __launch_bounds__(256) void cast8(const float* __restrict__ in,
                                             bf16* __restrict__ out, int n8) {
  int i = blockIdx.x * 256 + threadIdx.x;
  if (i >= n8) return;
  const float4* p = (const float4*)in;
  float4 a = p[2 * i], b = p[2 * i + 1];
  uint4 o = {(unsigned)f2b(a.x) | ((unsigned)f2b(a.y) << 16),
             (unsigned)f2b(a.z) | ((unsigned)f2b(a.w) << 16),
             (unsigned)f2b(b.x) | ((unsigned)f2b(b.y) << 16),
             (unsigned)f2b(b.z) | ((unsigned)f2b(b.w) << 16)};
  ((uint4*)out)[i] = o;
}

// ---------- zero fill (for eowB pad rows) ----------
__global__ __launch_bounds__(256) void zero16(bf16* __restrict__ p, int n8) {
  int i = blockIdx.x * 256 + threadIdx.x;
  if (i < n8) ((uint4*)p)[i] = uint4{0, 0, 0, 0};
}

// ---------- transpose+cast: in (R,C) f32 -> out (C,R) bf16, batched over z ----------
__global__ void transpose_cast(const float* __restrict__ in, bf16* __restrict__ out,
                               int R, int C) {
  __shared__ float tile[32][33];
  int l = blockIdx.z;
  in += (size_t)l * R * C;
  out += (size_t)l * R * C;
  int c0 = blockIdx.x * 32, r0 = blockIdx.y * 32;
#pragma unroll
  for (int i = 0; i < 4; i++) {
    int r = r0 + threadIdx.y + i * 8;
    tile[threadIdx.y + i * 8][threadIdx.x] = in[(size_t)r * C + c0 + threadIdx.x];
  }
  __syncthreads();
#pragma unroll
  for (int i = 0; i < 4; i++) {
    int c = c0 + threadIdx.y + i * 8;
    out[(size_t)c * R + r0 + threadIdx.x] = (bf16)tile[threadIdx.x][threadIdx.y + i * 8];
  }
}

// ---------- embedding gather ----------
__global__ void gather_embed(const int* __restrict__ ids, const float* __restrict__ emb,
                             float* __restrict__ h) {
  int row = blockIdx.x;
  int id = ids[row];
  const float4* src = (const float4*)(emb + (size_t)id * Hd);
  float4* dst = (float4*)(h + (size_t)row * Hd);
  dst[threadIdx.x] = src[threadIdx.x];
}

// ---------- layernorm, one wave per row, with fused split-K reduce ----------
// MODE 0: x = h[row]                         (plain LN)
// MODE 1: x = h + fb[col] + p0 + p1; h = x   (finish gemm2 split-K + residual)
// MODE 2: x = p0 + p1 + fb[col];    h = x    (finish hp split-K, overwrite)
template <int MODE>
__global__ __launch_bounds__(256) void ln_rows(
    const float* __restrict__ h, const float* __restrict__ p0,
    const float* __restrict__ p1, const float* __restrict__ fb,
    const float* __restrict__ w, const float* __restrict__ b,
    float* __restrict__ hout, bf16* __restrict__ y) {
  int row = blockIdx.x * 4 + (threadIdx.x >> 6);
  int lane = threadIdx.x & 63;
  size_t base = (size_t)row * Hd + lane * 8;
  float xv[8];
  if constexpr (MODE == 0) {
    *(float4*)&xv[0] = *(const float4*)(h + base);
    *(float4*)&xv[4] = *(const float4*)(h + base + 4);
  } else {
    float4 q0 = *(const float4*)(p0 + base), q1 = *(const float4*)(p0 + base + 4);
    float4 r0 = *(const float4*)(p1 + base), r1 = *(const float4*)(p1 + base + 4);
    float4 f0 = *(const float4*)(fb + lane * 8), f1 = *(const float4*)(fb + lane * 8 + 4);
    xv[0] = q0.x + r0.x + f0.x; xv[1] = q0.y + r0.y + f0.y;
    xv[2] = q0.z + r0.z + f0.z; xv[3] = q0.w + r0.w + f0.w;
    xv[4] = q1.x + r1.x + f1.x; xv[5] = q1.y + r1.y + f1.y;
    xv[6] = q1.z + r1.z + f1.z; xv[7] = q1.w + r1.w + f1.w;
    if constexpr (MODE == 1) {
      float4 a0 = *(const float4*)(h + base), a1 = *(const float4*)(h + base + 4);
      xv[0] += a0.x; xv[1] += a0.y; xv[2] += a0.z; xv[3] += a0.w;
      xv[4] += a1.x; xv[5] += a1.y; xv[6] += a1.z; xv[7] += a1.w;
    }
    *(float4*)(hout + base) = make_float4(xv[0], xv[1], xv[2], xv[3]);
    *(float4*)(hout + base + 4) = make_float4(xv[4], xv[5], xv[6], xv[7]);
  }
  float s = 0.f;
#pragma unroll
  for (int j = 0; j < 8; j++) s += xv[j];
#pragma unroll
  for (int off = 1; off < 64; off <<= 1) s += __shfl_xor(s, off);
  float mu = s * (1.0f / 512.0f);
  float s2 = 0.f;
#pragma unroll
  for (int j = 0; j < 8; j++) {
    xv[j] -= mu;
    s2 += xv[j] * xv[j];
  }
#pragma unroll
  for (int off = 1; off < 64; off <<= 1) s2 += __shfl_xor(s2, off);
  float scale = rsqrtf(s2 * (1.0f / 512.0f) + 1e-5f);
  float o[8];
#pragma unroll
  for (int j = 0; j < 8; j++) {
    float wj = w[lane * 8 + j], bj = b[lane * 8 + j];
    o[j] = xv[j] * scale * wj + bj;
  }
  uint4 pk = {(unsigned)f2b(o[0]) | ((unsigned)f2b(o[1]) << 16),
              (unsigned)f2b(o[2]) | ((unsigned)f2b(o[3]) << 16),
              (unsigned)f2b(o[4]) | ((unsigned)f2b(o[5]) << 16),
              (unsigned)f2b(o[6]) | ((unsigned)f2b(o[7]) << 16)};
  *(uint4*)(y + base) = pk;
}

// ---------- finish split-K gemm2 of stack1: h += fb + p0 + p1, also emit bf16 ----------
__global__ __launch_bounds__(256) void finish2(
    const float* __restrict__ p0, const float* __restrict__ p1,
    const float* __restrict__ fb, float* __restrict__ h, bf16* __restrict__ hbf) {
  int i = blockIdx.x * 256 + threadIdx.x;  // 8 elems each; grid covers 2M elems
  size_t base = (size_t)i * 8;
  int col = (int)(base & 511);
  float x[8];
#pragma unroll
  for (int j = 0; j < 8; j += 4) {
    float4 a = *(const float4*)(h + base + j);
    float4 q = *(const float4*)(p0 + base + j);
    float4 r = *(const float4*)(p1 + base + j);
    float4 f = *(const float4*)(fb + col + j);
    x[j] = a.x + q.x + r.x + f.x; x[j + 1] = a.y + q.y + r.y + f.y;
    x[j + 2] = a.z + q.z + r.z + f.z; x[j + 3] = a.w + q.w + r.w + f.w;
    *(float4*)(h + base + j) = make_float4(x[j], x[j + 1], x[j + 2], x[j + 3]);
  }
  uint4 pk = {(unsigned)f2b(x[0]) | ((unsigned)f2b(x[1]) << 16),
              (unsigned)f2b(x[2]) | ((unsigned)f2b(x[3]) << 16),
              (unsigned)f2b(x[4]) | ((unsigned)f2b(x[5]) << 16),
              (unsigned)f2b(x[6]) | ((unsigned)f2b(x[7]) << 16)};
  *(uint4*)(hbf + base) = pk;
}

// ---------- GEMM 128xBN tile, 256 thr, 3-slot pipeline, counted vmcnt ----------
// EPI 0: out_bf16 = gelu(acc + bias)
// EPI 4: out_f32[z*M*N + idx] = acc   (split-K partial)
template <int EPI, int BN, bool MSWZ>
__global__ __launch_bounds__(256) void gemm_bt(
    const bf16* __restrict__ A, const bf16* __restrict__ Bt,
    const float* __restrict__ bias, float* __restrict__ outF,
    bf16* __restrict__ outB, int M, int N, int Klen, int lda, int ldb) {
  constexpr int ASZ = 128 * 32;
  constexpr int BSZ = BN * 32;
  constexpr int TILE = ASZ + BSZ;
  __shared__ bf16 lds[3 * TILE];
  const int tid = threadIdx.x;
  const int wave = tid >> 6;
  const int lane = tid & 63;
  constexpr int NF = BN / 32;
  const int wm = (wave >> 1) * 64;
  const int wn = (wave & 1) * (BN / 2);

  int bm, bn;
  if constexpr (MSWZ) {
    const int per = gridDim.x >> 3;
    const int wg = (blockIdx.x & 7) * per + (blockIdx.x >> 3);
    const int nM = M >> 7;
    bm = wg & (nM - 1);
    bn = wg / nM;
  } else {
    bn = blockIdx.x;
    bm = blockIdx.y;
  }
  const int rowA0 = bm * 128;
  const int rowB0 = bn * BN;
  const int k0 = blockIdx.z * Klen;

  const bf16* srcA[2];
#pragma unroll
  for (int r = 0; r < 2; r++) {
    int c = (r * 4 + wave) * 64 + lane;
    srcA[r] = A + (size_t)(rowA0 + (c >> 2)) * lda + k0 + (c & 3) * 8;
  }
  const bf16* srcB[BN / 64];
#pragma unroll
  for (int r = 0; r < BN / 64; r++) {
    int c = (r * 4 + wave) * 64 + lane;
    srcB[r] = Bt + (size_t)(rowB0 + (c >> 2)) * ldb + k0 + (c & 3) * 8;
  }

  f32x4 acc[4][NF];
#pragma unroll
  for (int i = 0; i < 4; i++)
#pragma unroll
    for (int j = 0; j < NF; j++) acc[i][j] = (f32x4){0.f, 0.f, 0.f, 0.f};

  const int fr = lane & 15;
  const int ko = (lane >> 4) * 8;

  auto STAGE = [&](int slot) {
    bf16* dst = lds + slot * TILE;
#pragma unroll
    for (int r = 0; r < 2; r++) {
      load16_lds(srcA[r], dst + (r * 4 + wave) * 512);
      srcA[r] += 32;
    }
#pragma unroll
    for (int r = 0; r < BN / 64; r++) {
      load16_lds(srcB[r], dst + ASZ + (r * 4 + wave) * 512);
      srcB[r] += 32;
    }
  };

  STAGE(0);
  STAGE(1);
  const int nIter = Klen >> 5;
  int cur = 0, stg = 2;
  for (int it = 0; it < nIter; ++it) {
    if (it < nIter - 1) {
      if constexpr (BN == 64)
        asm volatile("s_waitcnt vmcnt(3)" ::: "memory");
      else
        asm volatile("s_waitcnt vmcnt(4)" ::: "memory");
    } else {
      asm volatile("s_waitcnt vmcnt(0)" ::: "memory");
    }
    __builtin_amdgcn_s_barrier();
    __builtin_amdgcn_sched_barrier(0);
    if (it + 2 < nIter) STAGE(stg);
    const bf16* lA = lds + cur * TILE;
    const bf16* lB = lA + ASZ;
    bf16x8 af[4], bfr[NF];
#pragma unroll
    for (int f = 0; f < 4; f++)
      af[f] = *(const bf16x8*)(lA + (wm + f * 16 + fr) * 32 + ko);
#pragma unroll
    for (int f = 0; f < NF; f++)
      bfr[f] = *(const bf16x8*)(lB + (wn + f * 16 + fr) * 32 + ko);
#pragma unroll
    for (int i = 0; i < 4; i++)
#pragma unroll
      for (int j = 0; j < NF; j++)
        acc[i][j] = __builtin_amdgcn_mfma_f32_16x16x32_bf16(af[i], bfr[j], acc[i][j], 0, 0, 0);
    cur = (cur == 2) ? 0 : cur + 1;
    stg = (stg == 2) ? 0 : stg + 1;
  }

  if constexpr (EPI == 4) outF += (size_t)blockIdx.z * M * N;
  const int orow = (lane >> 4) * 4;
  const int ocol = lane & 15;
#pragma unroll
  for (int i = 0; i < 4; i++) {
#pragma unroll
    for (int j = 0; j < NF; j++) {
      int row0 = rowA0 + wm + i * 16 + orow;
      int col = rowB0 + wn + j * 16 + ocol;
#pragma unroll
      for (int q = 0; q < 4; q++) {
        float v = acc[i][j][q];
        size_t idx = (size_t)(row0 + q) * N + col;
        if constexpr (EPI == 0) {
          outB[idx] = (bf16)gelu_tanh(v + bias[col]);
        } else {
          outF[idx] = v;
        }
      }
    }
  }
}

// ---------- GEMM 256x128 tile, 512 thr, 3-slot pipeline (gemm1) ----------
// 8 waves as 4M x 2N; loads/thread/STAGE = 2 (A) + 1 (B) = 3.
template <int EPI, bool MSWZ>
__global__ __launch_bounds__(512) void gemm_bt256(
    const bf16* __restrict__ A, const bf16* __restrict__ Bt,
    const float* __restrict__ bias, float* __restrict__ outF,
    bf16* __restrict__ outB, int M, int N, int lda, int ldb) {
  constexpr int ASZ = 256 * 32;
  constexpr int BSZ = 128 * 32;
  constexpr int TILE = ASZ + BSZ;  // 24 KB
  __shared__ bf16 lds[3 * TILE];   // 72 KB
  const int tid = threadIdx.x;
  const int wave = tid >> 6;
  const int lane = tid & 63;
  const int wm = (wave >> 1) * 64;
  const int wn = (wave & 1) * 64;

  int bm, bn;
  if constexpr (MSWZ) {
    const int per = gridDim.x >> 3;
    const int wg = (blockIdx.x & 7) * per + (blockIdx.x >> 3);
    const int nM = M >> 8;
    bm = wg & (nM - 1);
    bn = wg / nM;
  } else {
    bn = blockIdx.x;
    bm = blockIdx.y;
  }
  const int rowA0 = bm * 256;
  const int rowB0 = bn * 128;

  const bf16* srcA[2];
#pragma unroll
  for (int r = 0; r < 2; r++) {
    int c = r * 512 + tid;
    srcA[r] = A + (size_t)(rowA0 + (c >> 2)) * lda + (c & 3) * 8;
  }
  int cB = tid;
  const bf16* srcB = Bt + (size_t)(rowB0 + (cB >> 2)) * ldb + (cB & 3) * 8;

  f32x4 acc[4][4];
#pragma unroll
  for (int i = 0; i < 4; i++)
#pragma unroll
    for (int j = 0; j < 4; j++) acc[i][j] = (f32x4){0.f, 0.f, 0.f, 0.f};

  const int fr = lane & 15;
  const int ko = (lane >> 4) * 8;

  auto STAGE = [&](int slot) {
    bf16* dst = lds + slot * TILE;
#pragma unroll
    for (int r = 0; r < 2; r++) {
      load16_lds(srcA[r], dst + (r * 512 + tid) * 8);
      srcA[r] += 32;
    }
    load16_lds(srcB, dst + ASZ + tid * 8);
    srcB += 32;
  };

  STAGE(0);
  STAGE(1);
  const int nIter = 512 >> 5;
  int cur = 0, stg = 2;
  for (int it = 0; it < nIter; ++it) {
    if (it < nIter - 1)
      asm volatile("s_waitcnt vmcnt(3)" ::: "memory");
    else
      asm volatile("s_waitcnt vmcnt(0)" ::: "memory");
    __builtin_amdgcn_s_barrier();
    __builtin_amdgcn_sched_barrier(0);
    if (it + 2 < nIter) STAGE(stg);
    const bf16* lA = lds + cur * TILE;
    const bf16* lB = lA + ASZ;
    bf16x8 af[4], bfr[4];
#pragma unroll
    for (int f = 0; f < 4; f++)
      af[f] = *(const bf16x8*)(lA + (wm + f * 16 + fr) * 32 + ko);
#pragma unroll
    for (int f = 0; f < 4; f++)
      bfr[f] = *(const bf16x8*)(lB + (wn + f * 16 + fr) * 32 + ko);
#pragma unroll
    for (int i = 0; i < 4; i++)
#pragma unroll
      for (int j = 0; j < 4; j++)
        acc[i][j] = __builtin_amdgcn_mfma_f32_16x16x32_bf16(af[i], bfr[j], acc[i][j], 0, 0, 0);
    cur = (cur == 2) ? 0 : cur + 1;
    stg = (stg == 2) ? 0 : stg + 1;
  }

  const int orow = (lane >> 4) * 4;
  const int ocol = lane & 15;
#pragma unroll
  for (int i = 0; i < 4; i++) {
#pragma unroll
    for (int j = 0; j < 4; j++) {
      int row0 = rowA0 + wm + i * 16 + orow;
      int col = rowB0 + wn + j * 16 + ocol;
#pragma unroll
      for (int q = 0; q < 4; q++) {
        float v = acc[i][j][q];
        size_t idx = (size_t)(row0 + q) * N + col;
        if constexpr (EPI == 0) {
          outB[idx] = (bf16)gelu_tanh(v + bias[col]);
        } else {
          outF[idx] = v;
        }
      }
    }
  }
}

// ---------- logits GEMM: 256x256 tile, 512 thr, 3-slot pipeline, XCD swizzle ----------
// 8 waves as 2M x 4N; each wave 128x64 (32 MFMA/K-step). B is padded to Npad rows;
// stores guarded by col < N. Loads/thread/STAGE = 2 (A) + 2 (B) = 4.
__global__ __launch_bounds__(512, 1) void gemm_logits(
    const bf16* __restrict__ A, const bf16* __restrict__ Bt,
    float* __restrict__ outF, int M, int N, int lda, int ldb) {
  constexpr int ASZ = 256 * 32;
  constexpr int BSZ = 256 * 32;
  constexpr int TILE = ASZ + BSZ;  // 32 KB
  __shared__ bf16 lds[3 * TILE];   // 96 KB
  const int tid = threadIdx.x;
  const int wave = tid >> 6;
  const int lane = tid & 63;
  const int wm = (wave >> 2) * 128;  // 0,128
  const int wn = (wave & 3) * 64;    // 0,64,128,192

  // bijective XCD swizzle (gridDim.x = 3152, %8==0), M-panel inner (nM=16, pow2)
  const int per = gridDim.x >> 3;
  const int wg = (blockIdx.x & 7) * per + (blockIdx.x >> 3);
  const int bm = wg & 15;
  const int bn = wg >> 4;
  const int rowA0 = bm * 256;
  const int rowB0 = bn * 256;

  const bf16* srcA[2];
  const bf16* srcB[2];
#pragma unroll
  for (int r = 0; r < 2; r++) {
    int c = r * 512 + tid;  // 1024 chunks over 256x32
    srcA[r] = A + (size_t)(rowA0 + (c >> 2)) * lda + (c & 3) * 8;
    srcB[r] = Bt + (size_t)(rowB0 + (c >> 2)) * ldb + (c & 3) * 8;
  }

  f32x4 acc[8][4];
#pragma unroll
  for (int i = 0; i < 8; i++)
#pragma unroll
    for (int j = 0; j < 4; j++) acc[i][j] = (f32x4){0.f, 0.f, 0.f, 0.f};

  const int fr = lane & 15;
  const int ko = (lane >> 4) * 8;

  auto STAGE = [&](int slot) {
    bf16* dst = lds + slot * TILE;
#pragma unroll
    for (int r = 0; r < 2; r++) {
      load16_lds(srcA[r], dst + (r * 512 + tid) * 8);
      srcA[r] += 32;
      load16_lds(srcB[r], dst + ASZ + (r * 512 + tid) * 8);
      srcB[r] += 32;
    }
  };

  STAGE(0);
  STAGE(1);
  const int nIter = 512 >> 5;  // K = 512
  int cur = 0, stg = 2;
  for (int it = 0; it < nIter; ++it) {
    if (it < nIter - 1)
      asm volatile("s_waitcnt vmcnt(4)" ::: "memory");
    else
      asm volatile("s_waitcnt vmcnt(0)" ::: "memory");
    __builtin_amdgcn_s_barrier();
    __builtin_amdgcn_sched_barrier(0);
    if (it + 2 < nIter) STAGE(stg);
    const bf16* lA = lds + cur * TILE;
    const bf16* lB = lA + ASZ;
    bf16x8 af[8], bfr[4];
#pragma unroll
    for (int f = 0; f < 8; f++)
      af[f] = *(const bf16x8*)(lA + (wm + f * 16 + fr) * 32 + ko);
#pragma unroll
    for (int f = 0; f < 4; f++)
      bfr[f] = *(const bf16x8*)(lB + (wn + f * 16 + fr) * 32 + ko);
#pragma unroll
    for (int i = 0; i < 8; i++)
#pragma unroll
      for (int j = 0; j < 4; j++)
        acc[i][j] = __builtin_amdgcn_mfma_f32_16x16x32_bf16(af[i], bfr[j], acc[i][j], 0, 0, 0);
    cur = (cur == 2) ? 0 : cur + 1;
    stg = (stg == 2) ? 0 : stg + 1;
  }

  const int orow = (lane >> 4) * 4;
  const int ocol = lane & 15;
#pragma unroll
  for (int i = 0; i < 8; i++) {
#pragma unroll
    for (int j = 0; j < 4; j++) {
      int row0 = rowA0 + wm + i * 16 + orow;
      int col = rowB0 + wn + j * 16 + ocol;
      if (col < N) {
#pragma unroll
        for (int q = 0; q < 4; q++)
          outF[(size_t)(row0 + q) * N + col] = acc[i][j][q];
      }
    }
  }
}

// ---------- final hidden: h[:, -1, :] -> out ----------
__global__ void tail_copy(const float* __restrict__ h, float* __restrict__ out) {
  int t = blockIdx.x * 256 + threadIdx.x;  // 0..2047
  int b = t >> 9, k = t & 511;
  out[t] = h[((size_t)(b * 1024 + 1023)) * Hd + k];
}

// ---------- launch ----------
extern "C" void kernel_launch(void* const* d_in, const int* in_sizes, int n_in,
                              void* d_out, int out_size, void* d_ws, size_t ws_size,
                              hipStream_t stream) {
  const int* ids = (const int*)d_in[0];
  const float* emb = (const float*)d_in[1];
  const float* hp_w = (const float*)d_in[2];
  const float* hp_b = (const float*)d_in[3];
  const float* ln_w = (const float*)d_in[4];
  const float* ln_b = (const float*)d_in[5];
  const float* W1 = (const float*)d_in[6];
  const float* b1 = (const float*)d_in[7];
  const float* W2 = (const float*)d_in[8];
  const float* b2 = (const float*)d_in[9];
  const float* lnf_w = (const float*)d_in[10];
  const float* lnf_b = (const float*)d_in[11];
  const float* eow = (const float*)d_in[12];
  float* out = (float*)d_out;

  char* ws = (char*)d_ws;
  float* h = (float*)(ws);                          // 8 MB
  bf16* ybf = (bf16*)(ws + (8u << 20));             // 4 MB
  bf16* abf = (bf16*)(ws + (12u << 20));            // 16 MB
  bf16* W1t = (bf16*)(ws + (28u << 20));            // 12 MB
  bf16* W2t = (bf16*)(ws + (40u << 20));            // 12 MB
  bf16* hpwB = (bf16*)(ws + (52u << 20));           // 0.5 MB
  bf16* eowB = (bf16*)(ws + (53u << 20));           // 51.6 MB (padded to Vpad rows)

  // split-K partials live in d_out's logits region (overwritten by logits GEMM later)
  float* p0 = out;                    // 2M floats
  float* p1 = out + (size_t)Md * Hd;  // next 2M floats

  // weight prep
  cast8<<<dim3(Vd * Hd / 8 / 256), dim3(256), 0, stream>>>(eow, eowB, Vd * Hd / 8);
  zero16<<<dim3((Vpad - Vd) * Hd / 8 / 256), dim3(256), 0, stream>>>(
      eowB + (size_t)Vd * Hd, (Vpad - Vd) * Hd / 8);
  cast8<<<dim3(Hd * Hd / 8 / 256), dim3(256), 0, stream>>>(hp_w, hpwB, Hd * Hd / 8);
  transpose_cast<<<dim3(Fd / 32, Hd / 32, Ld), dim3(32, 8), 0, stream>>>(W1, W1t, Hd, Fd);
  transpose_cast<<<dim3(Hd / 32, Fd / 32, Ld), dim3(32, 8), 0, stream>>>(W2, W2t, Fd, Hd);

  gather_embed<<<dim3(Md), dim3(128), 0, stream>>>(ids, emb, h);

  // one MLP layer: ln (with optional fused finish) -> gemm1(256x128) -> split-K gemm2
  auto layer = [&](int l, int mode, const float* fb, const float* lw, const float* lb) {
    if (mode == 0)
      ln_rows<0><<<dim3(Md / 4), dim3(256), 0, stream>>>(h, p0, p1, fb, lw, lb, h, ybf);
    else if (mode == 1)
      ln_rows<1><<<dim3(Md / 4), dim3(256), 0, stream>>>(h, p0, p1, fb, lw, lb, h, ybf);
    else
      ln_rows<2><<<dim3(Md / 4), dim3(256), 0, stream>>>(h, p0, p1, fb, lw, lb, h, ybf);
    gemm_bt256<0, false><<<dim3(Fd / 128, Md / 256), dim3(512), 0, stream>>>(
        ybf, W1t + (size_t)l * Fd * Hd, b1 + (size_t)l * Fd, (float*)nullptr, abf,
        Md, Fd, Hd, Hd);
    gemm_bt<4, 128, false><<<dim3(Hd / 128, Md / 128, 2), dim3(256), 0, stream>>>(
        abf, W2t + (size_t)l * Hd * Fd, (const float*)nullptr, p0, (bf16*)nullptr,
        Md, Hd, Fd / 2, Fd, Fd);
  };

  // ---- stack 1 ----
  layer(0, 0, nullptr, ln_w, ln_b);
  for (int l = 1; l < Ld; l++)
    layer(l, 1, b2 + (size_t)(l - 1) * Hd, ln_w + (size_t)l * Hd, ln_b + (size_t)l * Hd);
  finish2<<<dim3(Md * Hd / 8 / 256), dim3(256), 0, stream>>>(
      p0, p1, b2 + (size_t)(Ld - 1) * Hd, h, ybf);

  // ---- hp projection (split-K=2, BN=128, finish fused into next LN) ----
  gemm_bt<4, 128, false><<<dim3(Hd / 128, Md / 128, 2), dim3(256), 0, stream>>>(
      ybf, hpwB, (const float*)nullptr, p0, (bf16*)nullptr, Md, Hd, Hd / 2, Hd, Hd);

  // ---- stack 2 ----
  layer(0, 2, hp_b, ln_w, ln_b);
  for (int l = 1; l < Ld; l++)
    layer(l, 1, b2 + (size_t)(l - 1) * Hd, ln_w + (size_t)l * Hd, ln_b + (size_t)l * Hd);

  // ---- final LN (fused finish of last gemm2) + logits (256x256, XCD swizzle) ----
  ln_rows<1><<<dim3(Md / 4), dim3(256), 0, stream>>>(
      h, p0, p1, b2 + (size_t)(Ld - 1) * Hd, lnf_w, lnf_b, h, ybf);
  gemm_logits<<<dim3((Vpad / 256) * (Md / 256)), dim3(512), 0, stream>>>(
      ybf, eowB, out, Md, Vd, Hd, Hd);

  // final hidden
  tail_copy<<<dim3(8), dim3(256), 0, stream>>>(h, out + (size_t)Md * Vd);
}

// Round 8
// 943.968 us; speedup vs baseline: 1.4755x; 1.0425x over previous
//
#include <hip/hip_runtime.h>
#include <hip/hip_bf16.h>
#include <cstdint>

using bf16 = __hip_bfloat16;
typedef __bf16 bf16x8 __attribute__((ext_vector_type(8)));
typedef float f32x4 __attribute__((ext_vector_type(4)));

constexpr int Hd = 512;
constexpr int Ld = 6;
constexpr int Fd = 2048;
constexpr int Vd = 50304;
constexpr int Vpad = 50432;  // 197*256
constexpr int Md = 4096;     // B*S = 4*1024

// ---------- helpers ----------
__device__ __forceinline__ unsigned short f2b(float x) {
  return __builtin_bit_cast(unsigned short, __float2bfloat16(x));
}

__device__ __forceinline__ float gelu_tanh(float x) {
  const float c = 0.7978845608028654f;  // sqrt(2/pi)
  float x3 = x * x * x;
  return 0.5f * x * (1.0f + tanhf(c * (x + 0.044715f * x3)));
}

__device__ __forceinline__ void load16_lds(const bf16* g, bf16* l) {
  __builtin_amdgcn_global_load_lds(
      (const __attribute__((address_space(1))) void*)g,
      (__attribute__((address_space(3))) void*)l, 16, 0, 0);
}

// ---------- cast fp32 -> bf16, 8 elems/thread ----------
__global__ __launch_bounds__(256) void cast8(const float* __restrict__ in,
                                             bf16* __restrict__ out, int n8) {
  int i = blockIdx.x * 256 + threadIdx.x;
  if (i >= n8) return;
  const float4* p = (const float4*)in;
  float4 a = p[2 * i], b = p[2 * i + 1];
  uint4 o = {(unsigned)f2b(a.x) | ((unsigned)f2b(a.y) << 16),
             (unsigned)f2b(a.z) | ((unsigned)f2b(a.w) << 16),
             (unsigned)f2b(b.x) | ((unsigned)f2b(b.y) << 16),
             (unsigned)f2b(b.z) | ((unsigned)f2b(b.w) << 16)};
  ((uint4*)out)[i] = o;
}

// ---------- zero fill (for eowB pad rows) ----------
__global__ __launch_bounds__(256) void zero16(bf16* __restrict__ p, int n8) {
  int i = blockIdx.x * 256 + threadIdx.x;
  if (i < n8) ((uint4*)p)[i] = uint4{0, 0, 0, 0};
}

// ---------- transpose+cast: in (R,C) f32 -> out (C,R) bf16, batched over z ----------
__global__ void transpose_cast(const float* __restrict__ in, bf16* __restrict__ out,
                               int R, int C) {
  __shared__ float tile[32][33];
  int l = blockIdx.z;
  in += (size_t)l * R * C;
  out += (size_t)l * R * C;
  int c0 = blockIdx.x * 32, r0 = blockIdx.y * 32;
#pragma unroll
  for (int i = 0; i < 4; i++) {
    int r = r0 + threadIdx.y + i * 8;
    tile[threadIdx.y + i * 8][threadIdx.x] = in[(size_t)r * C + c0 + threadIdx.x];
  }
  __syncthreads();
#pragma unroll
  for (int i = 0; i < 4; i++) {
    int c = c0 + threadIdx.y + i * 8;
    out[(size_t)c * R + r0 + threadIdx.x] = (bf16)tile[threadIdx.x][threadIdx.y + i * 8];
  }
}

// ---------- embedding gather ----------
__global__ void gather_embed(const int* __restrict__ ids, const float* __restrict__ emb,
                             float* __restrict__ h) {
  int row = blockIdx.x;
  int id = ids[row];
  const float4* src = (const float4*)(emb + (size_t)id * Hd);
  float4* dst = (float4*)(h + (size_t)row * Hd);
  dst[threadIdx.x] = src[threadIdx.x];
}

// ---------- layernorm, one wave per row, with fused split-K reduce ----------
// MODE 0: x = h[row]                         (plain LN)
// MODE 1: x = h + fb[col] + p0 + p1; h = x   (finish gemm2 split-K + residual)
// MODE 2: x = p0 + p1 + fb[col];    h = x    (finish hp split-K, overwrite)
template <int MODE>
__global__ __launch_bounds__(256) void ln_rows(
    const float* __restrict__ h, const float* __restrict__ p0,
    const float* __restrict__ p1, const float* __restrict__ fb,
    const float* __restrict__ w, const float* __restrict__ b,
    float* __restrict__ hout, bf16* __restrict__ y) {
  int row = blockIdx.x * 4 + (threadIdx.x >> 6);
  int lane = threadIdx.x & 63;
  size_t base = (size_t)row * Hd + lane * 8;
  float xv[8];
  if constexpr (MODE == 0) {
    *(float4*)&xv[0] = *(const float4*)(h + base);
    *(float4*)&xv[4] = *(const float4*)(h + base + 4);
  } else {
    float4 q0 = *(const float4*)(p0 + base), q1 = *(const float4*)(p0 + base + 4);
    float4 r0 = *(const float4*)(p1 + base), r1 = *(const float4*)(p1 + base + 4);
    float4 f0 = *(const float4*)(fb + lane * 8), f1 = *(const float4*)(fb + lane * 8 + 4);
    xv[0] = q0.x + r0.x + f0.x; xv[1] = q0.y + r0.y + f0.y;
    xv[2] = q0.z + r0.z + f0.z; xv[3] = q0.w + r0.w + f0.w;
    xv[4] = q1.x + r1.x + f1.x; xv[5] = q1.y + r1.y + f1.y;
    xv[6] = q1.z + r1.z + f1.z; xv[7] = q1.w + r1.w + f1.w;
    if constexpr (MODE == 1) {
      float4 a0 = *(const float4*)(h + base), a1 = *(const float4*)(h + base + 4);
      xv[0] += a0.x; xv[1] += a0.y; xv[2] += a0.z; xv[3] += a0.w;
      xv[4] += a1.x; xv[5] += a1.y; xv[6] += a1.z; xv[7] += a1.w;
    }
    *(float4*)(hout + base) = make_float4(xv[0], xv[1], xv[2], xv[3]);
    *(float4*)(hout + base + 4) = make_float4(xv[4], xv[5], xv[6], xv[7]);
  }
  float s = 0.f;
#pragma unroll
  for (int j = 0; j < 8; j++) s += xv[j];
#pragma unroll
  for (int off = 1; off < 64; off <<= 1) s += __shfl_xor(s, off);
  float mu = s * (1.0f / 512.0f);
  float s2 = 0.f;
#pragma unroll
  for (int j = 0; j < 8; j++) {
    xv[j] -= mu;
    s2 += xv[j] * xv[j];
  }
#pragma unroll
  for (int off = 1; off < 64; off <<= 1) s2 += __shfl_xor(s2, off);
  float scale = rsqrtf(s2 * (1.0f / 512.0f) + 1e-5f);
  float o[8];
#pragma unroll
  for (int j = 0; j < 8; j++) {
    float wj = w[lane * 8 + j], bj = b[lane * 8 + j];
    o[j] = xv[j] * scale * wj + bj;
  }
  uint4 pk = {(unsigned)f2b(o[0]) | ((unsigned)f2b(o[1]) << 16),
              (unsigned)f2b(o[2]) | ((unsigned)f2b(o[3]) << 16),
              (unsigned)f2b(o[4]) | ((unsigned)f2b(o[5]) << 16),
              (unsigned)f2b(o[6]) | ((unsigned)f2b(o[7]) << 16)};
  *(uint4*)(y + base) = pk;
}

// ---------- finish split-K gemm2 of stack1: h += fb + p0 + p1, also emit bf16 ----------
__global__ __launch_bounds__(256) void finish2(
    const float* __restrict__ p0, const float* __restrict__ p1,
    const float* __restrict__ fb, float* __restrict__ h, bf16* __restrict__ hbf) {
  int i = blockIdx.x * 256 + threadIdx.x;  // 8 elems each; grid covers 2M elems
  size_t base = (size_t)i * 8;
  int col = (int)(base & 511);
  float x[8];
#pragma unroll
  for (int j = 0; j < 8; j += 4) {
    float4 a = *(const float4*)(h + base + j);
    float4 q = *(const float4*)(p0 + base + j);
    float4 r = *(const float4*)(p1 + base + j);
    float4 f = *(const float4*)(fb + col + j);
    x[j] = a.x + q.x + r.x + f.x; x[j + 1] = a.y + q.y + r.y + f.y;
    x[j + 2] = a.z + q.z + r.z + f.z; x[j + 3] = a.w + q.w + r.w + f.w;
    *(float4*)(h + base + j) = make_float4(x[j], x[j + 1], x[j + 2], x[j + 3]);
  }
  uint4 pk = {(unsigned)f2b(x[0]) | ((unsigned)f2b(x[1]) << 16),
              (unsigned)f2b(x[2]) | ((unsigned)f2b(x[3]) << 16),
              (unsigned)f2b(x[4]) | ((unsigned)f2b(x[5]) << 16),
              (unsigned)f2b(x[6]) | ((unsigned)f2b(x[7]) << 16)};
  *(uint4*)(hbf + base) = pk;
}

// ============ GEMM kernels: BK=64, conflict-free XOR swizzle ============
// LDS layout per operand tile: rows of 64 bf16 (128B) = 8 chunks of 16B.
// Swizzle (both sides): LDS[row][d] holds global[row][d ^ (row&7)].
// Read of k-chunk kq (kq = ks*4 + (lane>>4)) at swizzled chunk kq ^ (row&7):
// 16-lane groups span all 8 bank-quads (rows 0..7) -> 2-way aliasing = free.

// ---------- GEMM 128x128 tile, BK=64, 256 thr, 3-slot counted-vmcnt ----------
// EPI 0: out_bf16 = gelu(acc + bias)
// EPI 4: out_f32[z*M*N + idx] = acc   (split-K partial)
template <int EPI>
__global__ __launch_bounds__(256) void gemm_bt(
    const bf16* __restrict__ A, const bf16* __restrict__ Bt,
    const float* __restrict__ bias, float* __restrict__ outF,
    bf16* __restrict__ outB, int M, int N, int Klen, int lda, int ldb) {
  constexpr int ASZ = 128 * 64;          // 8192 elems
  constexpr int TILE = 2 * ASZ;          // A + B = 32 KB
  __shared__ bf16 lds[3 * TILE];         // 96 KB
  const int tid = threadIdx.x;
  const int wave = tid >> 6;
  const int lane = tid & 63;
  const int wm = (wave >> 1) * 64;
  const int wn = (wave & 1) * 64;

  const int bn = blockIdx.x;
  const int bm = blockIdx.y;
  const int rowA0 = bm * 128;
  const int rowB0 = bn * 128;
  const int k0 = blockIdx.z * Klen;

  // staging sources (chunk c = r*256+tid; row=c>>3, d=c&7, global cw = d^(row&7))
  const bf16* srcA[4];
  const bf16* srcB[4];
#pragma unroll
  for (int r = 0; r < 4; r++) {
    int c = r * 256 + tid;
    int row = c >> 3, d = c & 7;
    int cw = d ^ (row & 7);
    srcA[r] = A + (size_t)(rowA0 + row) * lda + k0 + cw * 8;
    srcB[r] = Bt + (size_t)(rowB0 + row) * ldb + k0 + cw * 8;
  }

  f32x4 acc[4][4];
#pragma unroll
  for (int i = 0; i < 4; i++)
#pragma unroll
    for (int j = 0; j < 4; j++) acc[i][j] = (f32x4){0.f, 0.f, 0.f, 0.f};

  const int fr = lane & 15;
  const int hi = lane >> 4;
  const int swz = fr & 7;

  auto STAGE = [&](int slot) {
    bf16* dst = lds + slot * TILE;
#pragma unroll
    for (int r = 0; r < 4; r++) {
      load16_lds(srcA[r], dst + (r * 4 + wave) * 512);
      srcA[r] += 64;
      load16_lds(srcB[r], dst + ASZ + (r * 4 + wave) * 512);
      srcB[r] += 64;
    }
  };

  STAGE(0);
  STAGE(1);
  const int nIter = Klen >> 6;
  int cur = 0, stg = 2;
  for (int it = 0; it < nIter; ++it) {
    if (it < nIter - 1)
      asm volatile("s_waitcnt vmcnt(8)" ::: "memory");
    else
      asm volatile("s_waitcnt vmcnt(0)" ::: "memory");
    __builtin_amdgcn_s_barrier();
    __builtin_amdgcn_sched_barrier(0);
    if (it + 2 < nIter) STAGE(stg);
    const bf16* lA = lds + cur * TILE;
    const bf16* lB = lA + ASZ;
#pragma unroll
    for (int ks = 0; ks < 2; ks++) {
      bf16x8 af[4], bfr[4];
#pragma unroll
      for (int f = 0; f < 4; f++) {
        int rowa = wm + f * 16 + fr;
        af[f] = *(const bf16x8*)(lA + rowa * 64 + ((ks * 4 + hi) ^ swz) * 8);
        int rowb = wn + f * 16 + fr;
        bfr[f] = *(const bf16x8*)(lB + rowb * 64 + ((ks * 4 + hi) ^ swz) * 8);
      }
#pragma unroll
      for (int i = 0; i < 4; i++)
#pragma unroll
        for (int j = 0; j < 4; j++)
          acc[i][j] = __builtin_amdgcn_mfma_f32_16x16x32_bf16(af[i], bfr[j], acc[i][j], 0, 0, 0);
    }
    cur = (cur == 2) ? 0 : cur + 1;
    stg = (stg == 2) ? 0 : stg + 1;
  }

  if constexpr (EPI == 4) outF += (size_t)blockIdx.z * M * N;
  const int orow = hi * 4;
  const int ocol = fr;
#pragma unroll
  for (int i = 0; i < 4; i++) {
#pragma unroll
    for (int j = 0; j < 4; j++) {
      int row0 = rowA0 + wm + i * 16 + orow;
      int col = rowB0 + wn + j * 16 + ocol;
#pragma unroll
      for (int q = 0; q < 4; q++) {
        float v = acc[i][j][q];
        size_t idx = (size_t)(row0 + q) * N + col;
        if constexpr (EPI == 0) {
          outB[idx] = (bf16)gelu_tanh(v + bias[col]);
        } else {
          outF[idx] = v;
        }
      }
    }
  }
}

// ---------- GEMM 256x128 tile, BK=64, 512 thr, 3-slot counted-vmcnt (gemm1) ----------
// 8 waves as 4M x 2N. Loads/thread/STAGE: A 4 + B 2 = 6.
template <int EPI>
__global__ __launch_bounds__(512) void gemm_bt256(
    const bf16* __restrict__ A, const bf16* __restrict__ Bt,
    const float* __restrict__ bias, float* __restrict__ outF,
    bf16* __restrict__ outB, int M, int N, int lda, int ldb) {
  constexpr int ASZ = 256 * 64;          // 16384 elems (32 KB)
  constexpr int BSZ = 128 * 64;          // 8192 elems (16 KB)
  constexpr int TILE = ASZ + BSZ;        // 48 KB
  __shared__ bf16 lds[3 * TILE];         // 144 KB
  const int tid = threadIdx.x;
  const int wave = tid >> 6;
  const int lane = tid & 63;
  const int wm = (wave >> 1) * 64;
  const int wn = (wave & 1) * 64;

  const int bn = blockIdx.x;
  const int bm = blockIdx.y;
  const int rowA0 = bm * 256;
  const int rowB0 = bn * 128;

  const bf16* srcA[4];
#pragma unroll
  for (int r = 0; r < 4; r++) {
    int c = r * 512 + tid;
    int row = c >> 3, d = c & 7;
    int cw = d ^ (row & 7);
    srcA[r] = A + (size_t)(rowA0 + row) * lda + cw * 8;
  }
  const bf16* srcB[2];
#pragma unroll
  for (int r = 0; r < 2; r++) {
    int c = r * 512 + tid;
    int row = c >> 3, d = c & 7;
    int cw = d ^ (row & 7);
    srcB[r] = Bt + (size_t)(rowB0 + row) * ldb + cw * 8;
  }

  f32x4 acc[4][4];
#pragma unroll
  for (int i = 0; i < 4; i++)
#pragma unroll
    for (int j = 0; j < 4; j++) acc[i][j] = (f32x4){0.f, 0.f, 0.f, 0.f};

  const int fr = lane & 15;
  const int hi = lane >> 4;
  const int swz = fr & 7;

  auto STAGE = [&](int slot) {
    bf16* dst = lds + slot * TILE;
#pragma unroll
    for (int r = 0; r < 4; r++) {
      load16_lds(srcA[r], dst + (r * 8 + wave) * 512);
      srcA[r] += 64;
    }
#pragma unroll
    for (int r = 0; r < 2; r++) {
      load16_lds(srcB[r], dst + ASZ + (r * 8 + wave) * 512);
      srcB[r] += 64;
    }
  };

  STAGE(0);
  STAGE(1);
  const int nIter = 512 >> 6;  // K = Hd = 512 -> 8 iters
  int cur = 0, stg = 2;
  for (int it = 0; it < nIter; ++it) {
    if (it < nIter - 1)
      asm volatile("s_waitcnt vmcnt(6)" ::: "memory");
    else
      asm volatile("s_waitcnt vmcnt(0)" ::: "memory");
    __builtin_amdgcn_s_barrier();
    __builtin_amdgcn_sched_barrier(0);
    if (it + 2 < nIter) STAGE(stg);
    const bf16* lA = lds + cur * TILE;
    const bf16* lB = lA + ASZ;
#pragma unroll
    for (int ks = 0; ks < 2; ks++) {
      bf16x8 af[4], bfr[4];
#pragma unroll
      for (int f = 0; f < 4; f++) {
        int rowa = wm + f * 16 + fr;
        af[f] = *(const bf16x8*)(lA + rowa * 64 + ((ks * 4 + hi) ^ swz) * 8);
        int rowb = wn + f * 16 + fr;
        bfr[f] = *(const bf16x8*)(lB + rowb * 64 + ((ks * 4 + hi) ^ swz) * 8);
      }
#pragma unroll
      for (int i = 0; i < 4; i++)
#pragma unroll
        for (int j = 0; j < 4; j++)
          acc[i][j] = __builtin_amdgcn_mfma_f32_16x16x32_bf16(af[i], bfr[j], acc[i][j], 0, 0, 0);
    }
    cur = (cur == 2) ? 0 : cur + 1;
    stg = (stg == 2) ? 0 : stg + 1;
  }

  const int orow = hi * 4;
  const int ocol = fr;
#pragma unroll
  for (int i = 0; i < 4; i++) {
#pragma unroll
    for (int j = 0; j < 4; j++) {
      int row0 = rowA0 + wm + i * 16 + orow;
      int col = rowB0 + wn + j * 16 + ocol;
#pragma unroll
      for (int q = 0; q < 4; q++) {
        float v = acc[i][j][q];
        size_t idx = (size_t)(row0 + q) * N + col;
        if constexpr (EPI == 0) {
          outB[idx] = (bf16)gelu_tanh(v + bias[col]);
        } else {
          outF[idx] = v;
        }
      }
    }
  }
}

// ---------- logits GEMM: 256x256 tile, BK=32, 512 thr, 3-slot, XCD swizzle ----------
// 8 waves as 2M x 4N; BK=32 swizzle: LDS[row][d] = global[row][d ^ ((row>>1)&3)].
__global__ __launch_bounds__(512, 1) void gemm_logits(
    const bf16* __restrict__ A, const bf16* __restrict__ Bt,
    float* __restrict__ outF, int M, int N, int lda, int ldb) {
  constexpr int ASZ = 256 * 32;
  constexpr int TILE = 2 * ASZ;    // 32 KB
  __shared__ bf16 lds[3 * TILE];   // 96 KB
  const int tid = threadIdx.x;
  const int wave = tid >> 6;
  const int lane = tid & 63;
  const int wm = (wave >> 2) * 128;  // 0,128
  const int wn = (wave & 3) * 64;    // 0,64,128,192

  // bijective XCD swizzle (gridDim.x = 3152, %8==0), M-panel inner (nM=16, pow2)
  const int per = gridDim.x >> 3;
  const int wg = (blockIdx.x & 7) * per + (blockIdx.x >> 3);
  const int bm = wg & 15;
  const int bn = wg >> 4;
  const int rowA0 = bm * 256;
  const int rowB0 = bn * 256;

  const bf16* srcA[2];
  const bf16* srcB[2];
#pragma unroll
  for (int r = 0; r < 2; r++) {
    int c = r * 512 + tid;  // 1024 chunks over 256x32
    int row = c >> 2, d = c & 3;
    int cw = d ^ ((row >> 1) & 3);
    srcA[r] = A + (size_t)(rowA0 + row) * lda + cw * 8;
    srcB[r] = Bt + (size_t)(rowB0 + row) * ldb + cw * 8;
  }

  f32x4 acc[8][4];
#pragma unroll
  for (int i = 0; i < 8; i++)
#pragma unroll
    for (int j = 0; j < 4; j++) acc[i][j] = (f32x4){0.f, 0.f, 0.f, 0.f};

  const int fr = lane & 15;
  const int hi = lane >> 4;
  const int sw32 = (fr >> 1) & 3;

  auto STAGE = [&](int slot) {
    bf16* dst = lds + slot * TILE;
#pragma unroll
    for (int r = 0; r < 2; r++) {
      load16_lds(srcA[r], dst + (r * 8 + wave) * 512);
      srcA[r] += 32;
      load16_lds(srcB[r], dst + ASZ + (r * 8 + wave) * 512);
      srcB[r] += 32;
    }
  };

  STAGE(0);
  STAGE(1);
  const int nIter = 512 >> 5;  // K = 512
  int cur = 0, stg = 2;
  for (int it = 0; it < nIter; ++it) {
    if (it < nIter - 1)
      asm volatile("s_waitcnt vmcnt(4)" ::: "memory");
    else
      asm volatile("s_waitcnt vmcnt(0)" ::: "memory");
    __builtin_amdgcn_s_barrier();
    __builtin_amdgcn_sched_barrier(0);
    if (it + 2 < nIter) STAGE(stg);
    const bf16* lA = lds + cur * TILE;
    const bf16* lB = lA + ASZ;
    bf16x8 af[8], bfr[4];
#pragma unroll
    for (int f = 0; f < 8; f++) {
      int rowa = wm + f * 16 + fr;
      af[f] = *(const bf16x8*)(lA + rowa * 32 + (hi ^ sw32) * 8);
    }
#pragma unroll
    for (int f = 0; f < 4; f++) {
      int rowb = wn + f * 16 + fr;
      bfr[f] = *(const bf16x8*)(lB + rowb * 32 + (hi ^ sw32) * 8);
    }
#pragma unroll
    for (int i = 0; i < 8; i++)
#pragma unroll
      for (int j = 0; j < 4; j++)
        acc[i][j] = __builtin_amdgcn_mfma_f32_16x16x32_bf16(af[i], bfr[j], acc[i][j], 0, 0, 0);
    cur = (cur == 2) ? 0 : cur + 1;
    stg = (stg == 2) ? 0 : stg + 1;
  }

  const int orow = hi * 4;
  const int ocol = fr;
#pragma unroll
  for (int i = 0; i < 8; i++) {
#pragma unroll
    for (int j = 0; j < 4; j++) {
      int row0 = rowA0 + wm + i * 16 + orow;
      int col = rowB0 + wn + j * 16 + ocol;
      if (col < N) {
#pragma unroll
        for (int q = 0; q < 4; q++)
          outF[(size_t)(row0 + q) * N + col] = acc[i][j][q];
      }
    }
  }
}

// ---------- final hidden: h[:, -1, :] -> out ----------
__global__ void tail_copy(const float* __restrict__ h, float* __restrict__ out) {
  int t = blockIdx.x * 256 + threadIdx.x;  // 0..2047
  int b = t >> 9, k = t & 511;
  out[t] = h[((size_t)(b * 1024 + 1023)) * Hd + k];
}

// ---------- launch ----------
extern "C" void kernel_launch(void* const* d_in, const int* in_sizes, int n_in,
                              void* d_out, int out_size, void* d_ws, size_t ws_size,
                              hipStream_t stream) {
  const int* ids = (const int*)d_in[0];
  const float* emb = (const float*)d_in[1];
  const float* hp_w = (const float*)d_in[2];
  const float* hp_b = (const float*)d_in[3];
  const float* ln_w = (const float*)d_in[4];
  const float* ln_b = (const float*)d_in[5];
  const float* W1 = (const float*)d_in[6];
  const float* b1 = (const float*)d_in[7];
  const float* W2 = (const float*)d_in[8];
  const float* b2 = (const float*)d_in[9];
  const float* lnf_w = (const float*)d_in[10];
  const float* lnf_b = (const float*)d_in[11];
  const float* eow = (const float*)d_in[12];
  float* out = (float*)d_out;

  char* ws = (char*)d_ws;
  float* h = (float*)(ws);                          // 8 MB
  bf16* ybf = (bf16*)(ws + (8u << 20));             // 4 MB
  bf16* abf = (bf16*)(ws + (12u << 20));            // 16 MB
  bf16* W1t = (bf16*)(ws + (28u << 20));            // 12 MB
  bf16* W2t = (bf16*)(ws + (40u << 20));            // 12 MB
  bf16* hpwB = (bf16*)(ws + (52u << 20));           // 0.5 MB
  bf16* eowB = (bf16*)(ws + (53u << 20));           // 51.6 MB (padded to Vpad rows)

  // split-K partials live in d_out's logits region (overwritten by logits GEMM later)
  float* p0 = out;                    // 2M floats
  float* p1 = out + (size_t)Md * Hd;  // next 2M floats

  // weight prep
  cast8<<<dim3(Vd * Hd / 8 / 256), dim3(256), 0, stream>>>(eow, eowB, Vd * Hd / 8);
  zero16<<<dim3((Vpad - Vd) * Hd / 8 / 256), dim3(256), 0, stream>>>(
      eowB + (size_t)Vd * Hd, (Vpad - Vd) * Hd / 8);
  cast8<<<dim3(Hd * Hd / 8 / 256), dim3(256), 0, stream>>>(hp_w, hpwB, Hd * Hd / 8);
  transpose_cast<<<dim3(Fd / 32, Hd / 32, Ld), dim3(32, 8), 0, stream>>>(W1, W1t, Hd, Fd);
  transpose_cast<<<dim3(Hd / 32, Fd / 32, Ld), dim3(32, 8), 0, stream>>>(W2, W2t, Fd, Hd);

  gather_embed<<<dim3(Md), dim3(128), 0, stream>>>(ids, emb, h);

  // one MLP layer: ln (with optional fused finish) -> gemm1(256x128) -> split-K gemm2
  auto layer = [&](int l, int mode, const float* fb, const float* lw, const float* lb) {
    if (mode == 0)
      ln_rows<0><<<dim3(Md / 4), dim3(256), 0, stream>>>(h, p0, p1, fb, lw, lb, h, ybf);
    else if (mode == 1)
      ln_rows<1><<<dim3(Md / 4), dim3(256), 0, stream>>>(h, p0, p1, fb, lw, lb, h, ybf);
    else
      ln_rows<2><<<dim3(Md / 4), dim3(256), 0, stream>>>(h, p0, p1, fb, lw, lb, h, ybf);
    gemm_bt256<0><<<dim3(Fd / 128, Md / 256), dim3(512), 0, stream>>>(
        ybf, W1t + (size_t)l * Fd * Hd, b1 + (size_t)l * Fd, (float*)nullptr, abf,
        Md, Fd, Hd, Hd);
    gemm_bt<4><<<dim3(Hd / 128, Md / 128, 2), dim3(256), 0, stream>>>(
        abf, W2t + (size_t)l * Hd * Fd, (const float*)nullptr, p0, (bf16*)nullptr,
        Md, Hd, Fd / 2, Fd, Fd);
  };

  // ---- stack 1 ----
  layer(0, 0, nullptr, ln_w, ln_b);
  for (int l = 1; l < Ld; l++)
    layer(l, 1, b2 + (size_t)(l - 1) * Hd, ln_w + (size_t)l * Hd, ln_b + (size_t)l * Hd);
  finish2<<<dim3(Md * Hd / 8 / 256), dim3(256), 0, stream>>>(
      p0, p1, b2 + (size_t)(Ld - 1) * Hd, h, ybf);

  // ---- hp projection (split-K=2, finish fused into next LN) ----
  gemm_bt<4><<<dim3(Hd / 128, Md / 128, 2), dim3(256), 0, stream>>>(
      ybf, hpwB, (const float*)nullptr, p0, (bf16*)nullptr, Md, Hd, Hd / 2, Hd, Hd);

  // ---- stack 2 ----
  layer(0, 2, hp_b, ln_w, ln_b);
  for (int l = 1; l < Ld; l++)
    layer(l, 1, b2 + (size_t)(l - 1) * Hd, ln_w + (size_t)l * Hd, ln_b + (size_t)l * Hd);

  // ---- final LN (fused finish of last gemm2) + logits (256x256, XCD swizzle) ----
  ln_rows<1><<<dim3(Md / 4), dim3(256), 0, stream>>>(
      h, p0, p1, b2 + (size_t)(Ld - 1) * Hd, lnf_w, lnf_b, h, ybf);
  gemm_logits<<<dim3((Vpad / 256) * (Md / 256)), dim3(512), 0, stream>>>(
      ybf, eowB, out, Md, Vd, Hd, Hd);

  // final hidden
  tail_copy<<<dim3(8), dim3(256), 0, stream>>>(h, out + (size_t)Md * Vd);
}